// Round 4
// baseline (19482.155 us; speedup 1.0000x reference)
//
#include <hip/hip_runtime.h>
#include <cstddef>

#define T_STEPS 256
#define NSAT    1024
#define GSAT    2048
#define HID     256
#define IN_DIM  32
#define KTOT    288   // HID + IN_DIM
#define NBLK    256

typedef short  s16x8 __attribute__((ext_vector_type(8)));
typedef float  f32x4 __attribute__((ext_vector_type(4)));
typedef unsigned short ushort_t;

__device__ inline ushort_t f2bf(float f) {
    unsigned u = __builtin_bit_cast(unsigned, f);
    u += 0x7fffu + ((u >> 16) & 1u);
    return (ushort_t)(u >> 16);
}
__device__ inline float bf2f(ushort_t h) {
    unsigned u = ((unsigned)h) << 16;
    return __builtin_bit_cast(float, u);
}
__device__ inline float sigm(float x) { return 1.f / (1.f + __expf(-x)); }
__device__ inline float tanh_(float x) {
    float a = fabsf(x);
    float e = __expf(-2.f * a);
    float r = (1.f - e) / (1.f + e);
    return copysignf(r, x);
}

// ---------------- init: zero state + barrier region ----------------
__global__ void k_zero(float* p, size_t n) {
    size_t i = (size_t)blockIdx.x * blockDim.x + threadIdx.x;
    size_t stride = (size_t)gridDim.x * blockDim.x;
    for (; i < n; i += stride) p[i] = 0.f;
}

// ---------------- init: build BsatT [1024 cols][288 k] bf16 ----------------
__global__ void k_bconv(const float* __restrict__ r2s_rw,
                        const float* __restrict__ W_sat,
                        ushort_t* __restrict__ BsatT) {
    __shared__ ushort_t tile[32][72];
    int k0 = blockIdx.x * 32;
    int c0 = blockIdx.y * 64;
    int t  = threadIdx.x;
    int cc = t & 63, kq = (t >> 6) * 8;
#pragma unroll
    for (int j = 0; j < 8; j++) {
        int k = k0 + kq + j;
        int c = c0 + cc;
        int g = c >> 8, o = c & 255;
        float v = (k < 256) ? r2s_rw[((size_t)g * 256 + k) * 256 + o]
                            : W_sat[((size_t)g * 32 + (k - 256)) * 256 + o];
        tile[kq + j][cc] = f2bf(v);
    }
    __syncthreads();
    int cc2 = t >> 2, kq2 = (t & 3) * 8;
    ushort_t v[8];
#pragma unroll
    for (int j = 0; j < 8; j++) v[j] = tile[kq2 + j][cc2];
    ushort_t* dst = BsatT + (size_t)(c0 + cc2) * KTOT + k0 + kq2;
#pragma unroll
    for (int j = 0; j < 8; j++) dst[j] = v[j];
}

// ---------------- init: rl(0) = r2s_lb ----------------
__global__ void k_rl(const float* __restrict__ r2s_lb, float* __restrict__ rl_buf) {
    int i = blockIdx.x * 256 + threadIdx.x;
    if (i < 1024) rl_buf[i] = r2s_lb[i];
}

// ---------------- grid barrier (sense via generation counter) ----------------
__device__ __forceinline__ void gbar(unsigned* cnt, unsigned* gen, unsigned& my) {
    __syncthreads();
    if (threadIdx.x == 0) {
        my++;
        __threadfence();
        unsigned prev = __hip_atomic_fetch_add(cnt, 1u, __ATOMIC_ACQ_REL, __HIP_MEMORY_SCOPE_AGENT);
        if (prev == (unsigned)(NBLK - 1)) {
            __hip_atomic_store(cnt, 0u, __ATOMIC_RELAXED, __HIP_MEMORY_SCOPE_AGENT);
            __hip_atomic_store(gen, my, __ATOMIC_RELEASE, __HIP_MEMORY_SCOPE_AGENT);
        } else {
            while (__hip_atomic_load(gen, __ATOMIC_RELAXED, __HIP_MEMORY_SCOPE_AGENT) < my)
                __builtin_amdgcn_s_sleep(1);
        }
        __threadfence();
    }
    __syncthreads();
}

// ---------------- persistent kernel: whole T=256 recurrence ----------------
// Plain (non-cooperative) launch: 256 blocks x 256 threads on 256 CUs,
// ~19.5 KB LDS/block (cap ~8/CU) -> all blocks co-resident; hand-rolled
// atomic barriers provide the grid sync. hipLaunchCooperativeKernel was
// silently failing in this harness (R1/R2 absmax == stub-output absmax).
__launch_bounds__(256)
__global__ void k_persist(
    const float* __restrict__ x_rec, const float* __restrict__ x_sat,
    const float* __restrict__ y_true,
    const float* __restrict__ W_rec, const float* __restrict__ b_rec,
    const float* __restrict__ b_sat,
    const float* __restrict__ s2r_lw, const float* __restrict__ s2r_lb,
    const float* __restrict__ s2r_rw,
    const float* __restrict__ r2s_lw, const float* __restrict__ r2s_lb,
    const float* __restrict__ W_out, const float* __restrict__ b_out,
    const int* __restrict__ s_ids,
    const ushort_t* __restrict__ BsatT,
    unsigned* __restrict__ bar,
    float* __restrict__ mean_sum,
    ushort_t* __restrict__ Hg_bf, float* __restrict__ Cg,
    float* __restrict__ hrec, float* __restrict__ crec,
    float* __restrict__ rl_buf,
    ushort_t* __restrict__ Hnew_bf, float* __restrict__ Cnew,
    float* __restrict__ out)
{
    const int b = blockIdx.x, tid = threadIdx.x;
    const int bx = b & 7, by = b >> 3;   // o-tile, sat-tile
    unsigned my_gen = 0;
    unsigned* cnt = bar;
    unsigned* gen = bar + 1;
    unsigned* rec_cnt = bar + 2;

    __shared__ int   sid_s[32];
    __shared__ float rl_s[4][32];
    __shared__ float pre_s[32][129];
    __shared__ float hr_s[256];
    __shared__ float mh_s[256];
    __shared__ float xr_s[32];
    __shared__ float pre4[4][8];

    // MFMA lane constants
    const int w = tid >> 6, l = tid & 63;
    const int rt = w & 1;
    const int cfb = (w >> 1) * 4;
    const int row_l = rt * 16 + (l & 15);
    const int kb = (l >> 4) * 8;
    size_t brow[4];
#pragma unroll
    for (int q = 0; q < 4; q++) {
        int c = (cfb + q) * 16 + (l & 15);
        int g = c >> 5, ol = c & 31;
        brow[q] = ((size_t)(g * 256 + bx * 32 + ol)) * KTOT;
    }

    for (int t = 0; t < T_STEPS; t++) {
        // ================= phase 1: satellite GEMM + mean =================
        if (tid < 32) sid_s[tid] = s_ids[(size_t)t * NSAT + by * 32 + tid];
        __syncthreads();
        if (tid < 128) {
            int g = tid >> 5, ol = tid & 31;
            rl_s[g][ol] = rl_buf[g * 256 + bx * 32 + ol] + b_sat[g * 256 + bx * 32 + ol];
        }
        // mean partial: each block sums 4 of its tile's 32 rows
        {
            float s = 0.f;
#pragma unroll
            for (int n = bx * 4; n < bx * 4 + 4; n++)
                s += bf2f(Hg_bf[(size_t)sid_s[n] * HID + tid]);
            atomicAdd(&mean_sum[(size_t)t * HID + tid], s);
        }
        // MFMA: C[32 sats][128 gate-cols], K = 256 (h) + 32 (x)
        const int sidr = sid_s[row_l];
        const ushort_t* arow_h = Hg_bf + (size_t)sidr * HID;
        const float* arow_x = x_sat + ((size_t)t * NSAT + by * 32 + row_l) * IN_DIM;
        f32x4 acc[4];
#pragma unroll
        for (int q = 0; q < 4; q++) acc[q] = (f32x4){0.f, 0.f, 0.f, 0.f};
#pragma unroll
        for (int kc = 0; kc < 8; kc++) {
            int k0 = kc * 32 + kb;
            s16x8 af = *(const s16x8*)(arow_h + k0);
#pragma unroll
            for (int q = 0; q < 4; q++) {
                s16x8 bfv = *(const s16x8*)(BsatT + brow[q] + k0);
                acc[q] = __builtin_amdgcn_mfma_f32_16x16x32_bf16(af, bfv, acc[q], 0, 0, 0);
            }
        }
        {   // x tail (K = 256..287)
            f32x4 f0 = *(const f32x4*)(arow_x + kb);
            f32x4 f1 = *(const f32x4*)(arow_x + kb + 4);
            s16x8 af;
#pragma unroll
            for (int j = 0; j < 4; j++) af[j] = (short)f2bf(f0[j]);
#pragma unroll
            for (int j = 0; j < 4; j++) af[4 + j] = (short)f2bf(f1[j]);
            int k0 = 256 + kb;
#pragma unroll
            for (int q = 0; q < 4; q++) {
                s16x8 bfv = *(const s16x8*)(BsatT + brow[q] + k0);
                acc[q] = __builtin_amdgcn_mfma_f32_16x16x32_bf16(af, bfv, acc[q], 0, 0, 0);
            }
        }
#pragma unroll
        for (int q = 0; q < 4; q++) {
            int cbase = (cfb + q) * 16 + (l & 15);
#pragma unroll
            for (int r = 0; r < 4; r++)
                pre_s[rt * 16 + (l >> 4) * 4 + r][cbase] = acc[q][r];
        }
        __syncthreads();
#pragma unroll
        for (int p = 0; p < 4; p++) {
            int idx = tid + p * 256;
            int n = idx >> 5, ol = idx & 31;
            int og = bx * 32 + ol;
            float p0 = pre_s[n][0 * 32 + ol] + rl_s[0][ol];
            float p1 = pre_s[n][1 * 32 + ol] + rl_s[1][ol];
            float p2 = pre_s[n][2 * 32 + ol] + rl_s[2][ol];
            float p3 = pre_s[n][3 * 32 + ol] + rl_s[3][ol];
            float ig = sigm(p0), fg = sigm(p1), tg = tanh_(p2), oo = sigm(p3);
            float co = Cg[(size_t)sid_s[n] * HID + og];
            float cn = fg * co + ig * tg;
            float hn = oo * tanh_(cn);
            size_t woff = ((size_t)(by * 32 + n)) * HID + og;
            Hnew_bf[woff] = f2bf(hn);
            Cnew[woff] = cn;
        }
        gbar(cnt, gen, my_gen);

        // ================= phase 2: scatter || receiver chain =================
        if (b < 32) {
            // --- receiver LSTM for step t ---
            hr_s[tid] = (t > 0) ? hrec[(size_t)(t - 1) * HID + tid] : 0.f;
            mh_s[tid] = mean_sum[(size_t)t * HID + tid] * (1.f / 1024.f);
            if (tid < 32) xr_s[tid] = x_rec[(size_t)t * IN_DIM + tid];
            __syncthreads();
            const int combo = tid >> 3, sub = tid & 7;
            const int g = combo >> 3, oo2 = combo & 7;
            const int o = b * 8 + oo2;
            float part = 0.f;
            {
                const float* wr = s2r_rw + (size_t)g * HID * HID + o;
                const float* wl = s2r_lw + (size_t)g * HID * HID + o;
#pragma unroll 4
                for (int h = sub * 32; h < sub * 32 + 32; h++)
                    part += hr_s[h] * wr[(size_t)h * HID] + mh_s[h] * wl[(size_t)h * HID];
                const float* wx = W_rec + (size_t)g * IN_DIM * HID + o;
#pragma unroll
                for (int i = sub * 4; i < sub * 4 + 4; i++)
                    part += xr_s[i] * wx[(size_t)i * HID];
            }
            part += __shfl_down(part, 4);
            part += __shfl_down(part, 2);
            part += __shfl_down(part, 1);
            if (sub == 0) pre4[g][oo2] = part + b_rec[g * HID + o] + s2r_lb[g * HID + o];
            __syncthreads();
            if (tid < 8) {
                int o2 = b * 8 + tid;
                float p0 = pre4[0][tid], p1 = pre4[1][tid], p2 = pre4[2][tid], p3 = pre4[3][tid];
                float cp = (t > 0) ? crec[(size_t)(t - 1) * HID + o2] : 0.f;
                float ig = sigm(p0), fg = sigm(p1), tg = tanh_(p2), og = sigm(p3);
                float cn = fg * cp + ig * tg;
                float hn = og * tanh_(cn);
                crec[(size_t)t * HID + o2] = cn;
                hrec[(size_t)t * HID + o2] = hn;
            }
            __syncthreads();
            if (tid == 0) {
                __threadfence();
                __hip_atomic_fetch_add(rec_cnt, 1u, __ATOMIC_ACQ_REL, __HIP_MEMORY_SCOPE_AGENT);
                while (__hip_atomic_load(rec_cnt, __ATOMIC_RELAXED, __HIP_MEMORY_SCOPE_AGENT)
                       < 32u * (unsigned)(t + 1))
                    __builtin_amdgcn_s_sleep(1);
                __threadfence();
            }
            __syncthreads();
            // --- rl(t+1) = r2s_lw . h_rec(t) + r2s_lb  (32 gate-cols per block) ---
            hr_s[tid] = hrec[(size_t)t * HID + tid];
            __syncthreads();
            {
                const int idx = tid >> 3, sub2 = tid & 7;
                const int ci = b * 32 + idx;           // 0..1023
                const int g2 = ci >> 8, o3 = ci & 255;
                const float* wl2 = r2s_lw + (size_t)g2 * HID * HID + o3;
                float p2v = 0.f;
#pragma unroll 4
                for (int h = sub2 * 32; h < sub2 * 32 + 32; h++)
                    p2v += hr_s[h] * wl2[(size_t)h * HID];
                p2v += __shfl_down(p2v, 4);
                p2v += __shfl_down(p2v, 2);
                p2v += __shfl_down(p2v, 1);
                if (sub2 == 0) rl_buf[ci] = p2v + r2s_lb[ci];
            }
        } else {
            // --- scatter Hnew/Cnew -> Hg/Cg ---
            for (int n = b - 32; n < NSAT; n += 224) {
                int j = s_ids[(size_t)t * NSAT + n];
                Hg_bf[(size_t)j * HID + tid] = Hnew_bf[(size_t)n * HID + tid];
                Cg[(size_t)j * HID + tid]    = Cnew[(size_t)n * HID + tid];
            }
        }
        gbar(cnt, gen, my_gen);
    }

    // ================= final output =================
    if (b == 0) {
        __shared__ float red[256];
        float h = hrec[(size_t)255 * HID + tid];
        for (int j = 0; j < 2; j++) {
            red[tid] = h * W_out[tid * 2 + j];
            __syncthreads();
            for (int s = 128; s > 0; s >>= 1) {
                if (tid < s) red[tid] += red[tid + s];
                __syncthreads();
            }
            if (tid == 0) out[j] = red[0] + b_out[j];
            __syncthreads();
        }
        if (tid < 2) out[2 + tid] = y_true[tid];
    }
}

extern "C" void kernel_launch(void* const* d_in, const int* in_sizes, int n_in,
                              void* d_out, int out_size, void* d_ws, size_t ws_size,
                              hipStream_t stream) {
    (void)in_sizes; (void)n_in; (void)out_size; (void)ws_size;
    const float* x_rec  = (const float*)d_in[0];
    const float* x_sat  = (const float*)d_in[1];
    const float* y_true = (const float*)d_in[2];
    const float* W_rec  = (const float*)d_in[3];
    const float* b_rec  = (const float*)d_in[4];
    const float* W_sat  = (const float*)d_in[5];
    const float* b_sat  = (const float*)d_in[6];
    const float* s2r_lw = (const float*)d_in[7];
    const float* s2r_lb = (const float*)d_in[8];
    const float* s2r_rw = (const float*)d_in[9];
    const float* r2s_lw = (const float*)d_in[10];
    const float* r2s_lb = (const float*)d_in[11];
    const float* r2s_rw = (const float*)d_in[12];
    const float* W_out  = (const float*)d_in[13];
    const float* b_out  = (const float*)d_in[14];
    const int*   s_ids  = (const int*)d_in[15];

    float* ws = (float*)d_ws;
    // --- workspace map (f32 units) ---
    unsigned* bar      = (unsigned*)ws;                      // 64 slots
    float*    mean_sum = ws + 64;                            // 256*256          = 65536
    ushort_t* Hg_bf    = (ushort_t*)(ws + 64 + 65536);       // 2048*256 u16     = 262144 f32 slots
    float*    Cg       = ws + 64 + 65536 + 262144;           // 2048*256         = 524288
    float*    hrec     = Cg + 524288;                        // 256*256          = 65536
    float*    crec     = hrec + 65536;                       // 256*256          = 65536
    float*    rl_buf   = crec + 65536;                       // 1024
    ushort_t* Hnew_bf  = (ushort_t*)(rl_buf + 1024);         // 1024*256 u16     = 131072 f32 slots
    float*    Cnew     = rl_buf + 1024 + 131072;             // 1024*256         = 262144
    ushort_t* BsatT    = (ushort_t*)(Cnew + 262144);         // 1024*288 u16     = 147456 f32 slots

    // zero: bar + mean_sum + Hg_bf + Cg (contiguous prefix)
    const size_t zcount = 64 + 65536 + 262144 + 524288;
    hipLaunchKernelGGL(k_zero, dim3(2048), dim3(256), 0, stream, ws, zcount);
    hipLaunchKernelGGL(k_bconv, dim3(9, 16), dim3(256), 0, stream, r2s_rw, W_sat, BsatT);
    hipLaunchKernelGGL(k_rl, dim3(4), dim3(256), 0, stream, r2s_lb, rl_buf);

    // plain launch (NOT hipLaunchCooperativeKernel — it silently failed here)
    hipLaunchKernelGGL(k_persist, dim3(NBLK), dim3(256), 0, stream,
                       x_rec, x_sat, y_true,
                       W_rec, b_rec, b_sat,
                       s2r_lw, s2r_lb, s2r_rw,
                       r2s_lw, r2s_lb,
                       W_out, b_out,
                       s_ids, BsatT,
                       bar, mean_sum,
                       Hg_bf, Cg,
                       hrec, crec,
                       rl_buf,
                       Hnew_bf, Cnew,
                       (float*)d_out);
}

// Round 5
// 13459.685 us; speedup vs baseline: 1.4474x; 1.4474x over previous
//
#include <hip/hip_runtime.h>
#include <cstddef>

#define T_STEPS  256
#define NSAT     1024
#define GSAT     2048
#define HID      256
#define IN_DIM   32
#define KTOT     288   // HID + IN_DIM
#define NBLK_SAT 256
#define NBLK_TOT 288
#define GPB      36    // blocks per barrier counter group (288/8)

typedef short  s16x8 __attribute__((ext_vector_type(8)));
typedef float  f32x4 __attribute__((ext_vector_type(4)));
typedef unsigned short ushort_t;

__device__ inline ushort_t f2bf(float f) {
    unsigned u = __builtin_bit_cast(unsigned, f);
    u += 0x7fffu + ((u >> 16) & 1u);
    return (ushort_t)(u >> 16);
}
__device__ inline float bf2f(ushort_t h) {
    unsigned u = ((unsigned)h) << 16;
    return __builtin_bit_cast(float, u);
}
__device__ inline float sigm(float x) { return 1.f / (1.f + __expf(-x)); }
__device__ inline float tanh_(float x) {
    float a = fabsf(x);
    float e = __expf(-2.f * a);
    float r = (1.f - e) / (1.f + e);
    return copysignf(r, x);
}

// ---------------- init: zero prefix (bar + Hg_bf + Cg + pos_inv) ----------------
__global__ void k_zero(float* p, size_t n) {
    size_t i = (size_t)blockIdx.x * blockDim.x + threadIdx.x;
    size_t stride = (size_t)gridDim.x * blockDim.x;
    for (; i < n; i += stride) p[i] = 0.f;
}

// ---------------- init: BsatT [1024 cols][288 k] bf16 ----------------
__global__ void k_bconv(const float* __restrict__ r2s_rw,
                        const float* __restrict__ W_sat,
                        ushort_t* __restrict__ BsatT) {
    __shared__ ushort_t tile[32][72];
    int k0 = blockIdx.x * 32;
    int c0 = blockIdx.y * 64;
    int t  = threadIdx.x;
    int cc = t & 63, kq = (t >> 6) * 8;
#pragma unroll
    for (int j = 0; j < 8; j++) {
        int k = k0 + kq + j;
        int c = c0 + cc;
        int g = c >> 8, o = c & 255;
        float v = (k < 256) ? r2s_rw[((size_t)g * 256 + k) * 256 + o]
                            : W_sat[((size_t)g * 32 + (k - 256)) * 256 + o];
        tile[kq + j][cc] = f2bf(v);
    }
    __syncthreads();
    int cc2 = t >> 2, kq2 = (t & 3) * 8;
    ushort_t v[8];
#pragma unroll
    for (int j = 0; j < 8; j++) v[j] = tile[kq2 + j][cc2];
    ushort_t* dst = BsatT + (size_t)(c0 + cc2) * KTOT + k0 + kq2;
#pragma unroll
    for (int j = 0; j < 8; j++) dst[j] = v[j];
}

// ---------------- init: rl_bias = r2s_lb + b_sat ; rl_buf[0] = rl_bias ----------
__global__ void k_rlb(const float* __restrict__ r2s_lb, const float* __restrict__ b_sat,
                      float* __restrict__ rl_bias, float* __restrict__ rl_buf) {
    int i = blockIdx.x * 256 + threadIdx.x;
    if (i < 1024) { float v = r2s_lb[i] + b_sat[i]; rl_bias[i] = v; rl_buf[i] = v; }
}

// ---------------- init: pos_inv[t][j] = n+1 where s_ids[t][n] == j ----------------
__global__ void k_inv(const int* __restrict__ s_ids, int* __restrict__ pos_inv) {
    int t = blockIdx.x;
    for (int n = threadIdx.x; n < NSAT; n += 256)
        pos_inv[(size_t)t * GSAT + s_ids[(size_t)t * NSAT + n]] = n + 1;
}

// ---------------- init: transpose [4][256][256] h-major -> o-major ----------------
__global__ void k_wt(const float* __restrict__ in, float* __restrict__ outT) {
    __shared__ float tl[32][33];
    int g = blockIdx.z;
    int h0 = blockIdx.x * 32, o0 = blockIdx.y * 32;
    int lx = threadIdx.x & 31, ly = threadIdx.x >> 5;   // 32 x 8
#pragma unroll
    for (int i = 0; i < 32; i += 8)
        tl[ly + i][lx] = in[((size_t)g * 256 + h0 + ly + i) * 256 + o0 + lx];
    __syncthreads();
#pragma unroll
    for (int i = 0; i < 32; i += 8)
        outT[((size_t)g * 256 + o0 + ly + i) * 256 + h0 + lx] = tl[lx][ly + i];
}

// ---------------- grid barrier v2: 8 padded counters + 8 padded gens --------------
// monotonic (never reset); aggregator = block 255
__device__ __forceinline__ void gbar(unsigned* bar, int b, unsigned k) {
    __syncthreads();
    if (threadIdx.x == 0) {
        __threadfence();
        __hip_atomic_fetch_add(&bar[(b & 7) * 32], 1u, __ATOMIC_ACQ_REL, __HIP_MEMORY_SCOPE_AGENT);
    }
    if (b == NBLK_SAT - 1) {
        if (threadIdx.x < 8) {
            while (__hip_atomic_load(&bar[threadIdx.x * 32], __ATOMIC_RELAXED, __HIP_MEMORY_SCOPE_AGENT)
                   < GPB * k)
                __builtin_amdgcn_s_sleep(1);
        }
        __syncthreads();
        __threadfence();
        if (threadIdx.x < 8)
            __hip_atomic_store(&bar[256 + threadIdx.x * 32], k, __ATOMIC_RELEASE, __HIP_MEMORY_SCOPE_AGENT);
    } else {
        if (threadIdx.x == 0) {
            while (__hip_atomic_load(&bar[256 + (b & 7) * 32], __ATOMIC_RELAXED, __HIP_MEMORY_SCOPE_AGENT) < k)
                __builtin_amdgcn_s_sleep(1);
        }
        __syncthreads();
        __threadfence();
    }
}

// ---------------- rec-club sync (32 blocks, padded flags, monotonic) -------------
__device__ __forceinline__ void club_sync(unsigned* flags, int r, unsigned k) {
    __syncthreads();
    if (threadIdx.x == 0) {
        __threadfence();
        __hip_atomic_store(&flags[r * 32], k, __ATOMIC_RELEASE, __HIP_MEMORY_SCOPE_AGENT);
    }
    if (threadIdx.x < 32) {
        while (__hip_atomic_load(&flags[threadIdx.x * 32], __ATOMIC_RELAXED, __HIP_MEMORY_SCOPE_AGENT) < k)
            __builtin_amdgcn_s_sleep(1);
    }
    __syncthreads();
    __threadfence();
}

// ---------------- persistent kernel: one barrier per step ----------------
__launch_bounds__(256)
__global__ void k_persist(
    const float* __restrict__ x_rec, const float* __restrict__ x_sat,
    const float* __restrict__ y_true,
    const float* __restrict__ W_rec, const float* __restrict__ b_rec,
    const float* __restrict__ s2r_lb,
    const float* __restrict__ W_out, const float* __restrict__ b_out,
    const int* __restrict__ s_ids,
    const ushort_t* __restrict__ BsatT,
    unsigned* __restrict__ bar,
    ushort_t* __restrict__ Hg_bf, float* __restrict__ Cg,
    const int* __restrict__ pos_inv,
    float* __restrict__ meanpart,
    float* __restrict__ hrec, float* __restrict__ crec,
    float* __restrict__ rl_buf, const float* __restrict__ rl_bias,
    ushort_t* __restrict__ HnewA, ushort_t* __restrict__ HnewB,
    float* __restrict__ CnewA, float* __restrict__ CnewB,
    const float* __restrict__ s2r_rwT, const float* __restrict__ s2r_lwT,
    const float* __restrict__ r2s_lwT,
    float* __restrict__ out)
{
    const int b = blockIdx.x, tid = threadIdx.x;
    unsigned* flagA = bar + 512;
    unsigned* flagB = bar + 1536;

    __shared__ int   sid_s[32];
    __shared__ int   src_s[32];
    __shared__ float rl_s[4][32];
    __shared__ float pre_s[32][129];
    __shared__ float hr_s[256];
    __shared__ float mh_s[256];
    __shared__ float xr_s[32];
    __shared__ float pre4[4][8];

    if (b < NBLK_SAT) {
        // =============== satellite blocks: gather + GEMM + epilogue + scatter ======
        const int bx = b & 7, by = b >> 3;
        const int w = tid >> 6, l = tid & 63;
        const int rt = w & 1;
        const int cfb = (w >> 1) * 4;
        const int row_l = rt * 16 + (l & 15);
        const int kb = (l >> 4) * 8;
        size_t brow[4];
#pragma unroll
        for (int q = 0; q < 4; q++) {
            int c = (cfb + q) * 16 + (l & 15);
            int g = c >> 5, ol = c & 31;
            brow[q] = ((size_t)(g * 256 + bx * 32 + ol)) * KTOT;
        }

        for (int t = 0; t < T_STEPS; t++) {
            const ushort_t* HnP = (t & 1) ? HnewA : HnewB;
            ushort_t*       HnC = (t & 1) ? HnewB : HnewA;
            const float*    CnP = (t & 1) ? CnewA : CnewB;
            float*          CnC = (t & 1) ? CnewB : CnewA;

            if (tid < 32) {
                int j = s_ids[(size_t)t * NSAT + by * 32 + tid];
                sid_s[tid] = j;
                src_s[tid] = (t > 0) ? pos_inv[(size_t)(t - 1) * GSAT + j] - 1 : -1;
            }
            __syncthreads();
            if (tid < 128) {
                int g = tid >> 5, ol = tid & 31;
                rl_s[g][ol] = rl_buf[(size_t)(t & 1) * 1024 + g * 256 + bx * 32 + ol];
            }

            // --- MFMA GEMM: C[32 sats][128 gate-cols], K = 256(h) + 32(x) ---
            const int pa = src_s[row_l];
            const ushort_t* arow = (pa >= 0) ? HnP + (size_t)pa * HID
                                             : Hg_bf + (size_t)sid_s[row_l] * HID;
            const float* arow_x = x_sat + ((size_t)t * NSAT + by * 32 + row_l) * IN_DIM;
            f32x4 acc[4];
#pragma unroll
            for (int q = 0; q < 4; q++) acc[q] = (f32x4){0.f, 0.f, 0.f, 0.f};
#pragma unroll
            for (int kc = 0; kc < 8; kc++) {
                int k0 = kc * 32 + kb;
                s16x8 af = *(const s16x8*)(arow + k0);
#pragma unroll
                for (int q = 0; q < 4; q++) {
                    s16x8 bfv = *(const s16x8*)(BsatT + brow[q] + k0);
                    acc[q] = __builtin_amdgcn_mfma_f32_16x16x32_bf16(af, bfv, acc[q], 0, 0, 0);
                }
            }
            {   // x tail
                f32x4 f0 = *(const f32x4*)(arow_x + kb);
                f32x4 f1 = *(const f32x4*)(arow_x + kb + 4);
                s16x8 af;
#pragma unroll
                for (int j = 0; j < 4; j++) af[j] = (short)f2bf(f0[j]);
#pragma unroll
                for (int j = 0; j < 4; j++) af[4 + j] = (short)f2bf(f1[j]);
                int k0 = 256 + kb;
#pragma unroll
                for (int q = 0; q < 4; q++) {
                    s16x8 bfv = *(const s16x8*)(BsatT + brow[q] + k0);
                    acc[q] = __builtin_amdgcn_mfma_f32_16x16x32_bf16(af, bfv, acc[q], 0, 0, 0);
                }
            }
#pragma unroll
            for (int q = 0; q < 4; q++) {
                int cbase = (cfb + q) * 16 + (l & 15);
#pragma unroll
                for (int r = 0; r < 4; r++)
                    pre_s[rt * 16 + (l >> 4) * 4 + r][cbase] = acc[q][r];
            }
            __syncthreads();
            // --- epilogue: LSTM, write HnC/CnC ---
#pragma unroll
            for (int p = 0; p < 4; p++) {
                int idx = tid + p * 256;
                int n = idx >> 5, ol = idx & 31;
                int og = bx * 32 + ol;
                float p0 = pre_s[n][0 * 32 + ol] + rl_s[0][ol];
                float p1 = pre_s[n][1 * 32 + ol] + rl_s[1][ol];
                float p2 = pre_s[n][2 * 32 + ol] + rl_s[2][ol];
                float p3 = pre_s[n][3 * 32 + ol] + rl_s[3][ol];
                float ig = sigm(p0), fg = sigm(p1), tg = tanh_(p2), oo = sigm(p3);
                int pc = src_s[n];
                float co = (pc >= 0) ? CnP[(size_t)pc * HID + og]
                                     : Cg[(size_t)sid_s[n] * HID + og];
                float cn = fg * co + ig * tg;
                float hn = oo * tanh_(cn);
                size_t woff = ((size_t)(by * 32 + n)) * HID + og;
                HnC[woff] = f2bf(hn);
                CnC[woff] = cn;
            }
            // --- deferred scatter of step t-1 (disjoint from all step-t gathers) ---
            if (t > 0) {
                for (int n = b * 4; n < b * 4 + 4; n++) {
                    int jp = s_ids[(size_t)(t - 1) * NSAT + n];
                    Hg_bf[(size_t)jp * HID + tid] = HnP[(size_t)n * HID + tid];
                    Cg[(size_t)jp * HID + tid]    = CnP[(size_t)n * HID + tid];
                }
            }
            gbar(bar, b, (unsigned)(t + 1));
        }

        // --- final output (block 0) ---
        if (b == 0) {
            __shared__ float red[256];
            float h = hrec[(size_t)((T_STEPS - 1) & 1) * HID + tid];
            for (int j = 0; j < 2; j++) {
                red[tid] = h * W_out[tid * 2 + j];
                __syncthreads();
                for (int s = 128; s > 0; s >>= 1) {
                    if (tid < s) red[tid] += red[tid + s];
                    __syncthreads();
                }
                if (tid == 0) out[j] = red[0] + b_out[j];
                __syncthreads();
            }
            if (tid < 2) out[2 + tid] = y_true[tid];
        }
    } else {
        // =============== receiver club: mean -> rec LSTM -> rl(t+1) ===============
        const int r = b - NBLK_SAT;   // 0..31
        for (int t = 0; t < T_STEPS; t++) {
            const ushort_t* HnP = (t & 1) ? HnewA : HnewB;

            // A) mean partial over rows r*32 .. r*32+32 of gathered state
            float s = 0.f;
            for (int n = r * 32; n < r * 32 + 32; n++) {
                int j = s_ids[(size_t)t * NSAT + n];
                int p = (t > 0) ? pos_inv[(size_t)(t - 1) * GSAT + j] - 1 : -1;
                const ushort_t* hp = (p >= 0) ? HnP + (size_t)p * HID
                                              : Hg_bf + (size_t)j * HID;
                s += bf2f(hp[tid]);
            }
            meanpart[r * 256 + tid] = s;
            club_sync(flagA, r, (unsigned)(t + 1));

            // B) gather mean + h_rec(t-1) + x_rec(t) into LDS
            float mh = 0.f;
#pragma unroll 8
            for (int p2 = 0; p2 < 32; p2++) mh += meanpart[p2 * 256 + tid];
            mh_s[tid] = mh * (1.f / 1024.f);
            hr_s[tid] = (t > 0) ? hrec[(size_t)((t - 1) & 1) * HID + tid] : 0.f;
            if (tid < 32) xr_s[tid] = x_rec[(size_t)t * IN_DIM + tid];
            __syncthreads();

            // C) pre_rec matvec (transposed weights, f32x4 loads)
            const int combo = tid >> 3, sub = tid & 7;
            const int g = combo >> 3, oo2 = combo & 7;
            const int o = r * 8 + oo2;
            float part = 0.f;
            {
                const float* rwp = s2r_rwT + ((size_t)(g * 256 + o)) * 256 + sub * 32;
                const float* lwp = s2r_lwT + ((size_t)(g * 256 + o)) * 256 + sub * 32;
#pragma unroll
                for (int q = 0; q < 8; q++) {
                    f32x4 a = *(const f32x4*)(rwp + q * 4);
                    f32x4 c = *(const f32x4*)(lwp + q * 4);
#pragma unroll
                    for (int e = 0; e < 4; e++) {
                        int h = sub * 32 + q * 4 + e;
                        part += hr_s[h] * a[e] + mh_s[h] * c[e];
                    }
                }
                const float* wx = W_rec + (size_t)g * IN_DIM * HID + o;
#pragma unroll
                for (int i = sub * 4; i < sub * 4 + 4; i++)
                    part += xr_s[i] * wx[(size_t)i * HID];
            }
            part += __shfl_down(part, 4);
            part += __shfl_down(part, 2);
            part += __shfl_down(part, 1);
            if (sub == 0) pre4[g][oo2] = part + b_rec[g * HID + o] + s2r_lb[g * HID + o];
            __syncthreads();
            if (tid < 8) {
                int o2 = r * 8 + tid;
                float p0 = pre4[0][tid], p1 = pre4[1][tid], p2 = pre4[2][tid], p3 = pre4[3][tid];
                float cp = (t > 0) ? crec[(size_t)((t - 1) & 1) * HID + o2] : 0.f;
                float ig = sigm(p0), fg = sigm(p1), tg = tanh_(p2), og = sigm(p3);
                float cn = fg * cp + ig * tg;
                float hn = og * tanh_(cn);
                crec[(size_t)(t & 1) * HID + o2] = cn;
                hrec[(size_t)(t & 1) * HID + o2] = hn;
            }
            club_sync(flagB, r, (unsigned)(t + 1));

            // D) rl(t+1) = r2s_lwT . h_rec(t) + rl_bias   (32 cols per block)
            hr_s[tid] = hrec[(size_t)(t & 1) * HID + tid];
            __syncthreads();
            {
                const int idx = tid >> 3, sub2 = tid & 7;
                const int ci = r * 32 + idx;
                const float* wp = r2s_lwT + (size_t)ci * 256 + sub2 * 32;
                float p2v = 0.f;
#pragma unroll
                for (int q = 0; q < 8; q++) {
                    f32x4 w4 = *(const f32x4*)(wp + q * 4);
#pragma unroll
                    for (int e = 0; e < 4; e++)
                        p2v += hr_s[sub2 * 32 + q * 4 + e] * w4[e];
                }
                p2v += __shfl_down(p2v, 4);
                p2v += __shfl_down(p2v, 2);
                p2v += __shfl_down(p2v, 1);
                if (sub2 == 0)
                    rl_buf[(size_t)((t + 1) & 1) * 1024 + ci] = p2v + rl_bias[ci];
            }
            gbar(bar, b, (unsigned)(t + 1));
        }
    }
}

extern "C" void kernel_launch(void* const* d_in, const int* in_sizes, int n_in,
                              void* d_out, int out_size, void* d_ws, size_t ws_size,
                              hipStream_t stream) {
    (void)in_sizes; (void)n_in; (void)out_size; (void)ws_size;
    const float* x_rec  = (const float*)d_in[0];
    const float* x_sat  = (const float*)d_in[1];
    const float* y_true = (const float*)d_in[2];
    const float* W_rec  = (const float*)d_in[3];
    const float* b_rec  = (const float*)d_in[4];
    const float* W_sat  = (const float*)d_in[5];
    const float* b_sat  = (const float*)d_in[6];
    const float* s2r_lw = (const float*)d_in[7];
    const float* s2r_lb = (const float*)d_in[8];
    const float* s2r_rw = (const float*)d_in[9];
    const float* r2s_lw = (const float*)d_in[10];
    const float* r2s_lb = (const float*)d_in[11];
    const float* r2s_rw = (const float*)d_in[12];
    const float* W_out  = (const float*)d_in[13];
    const float* b_out  = (const float*)d_in[14];
    const int*   s_ids  = (const int*)d_in[15];

    float* ws = (float*)d_ws;
    size_t off = 0;
    unsigned* bar      = (unsigned*)(ws + off); off += 2560;
    ushort_t* Hg_bf    = (ushort_t*)(ws + off); off += 262144;  // 2048*256 u16
    float*    Cg       = ws + off;              off += 524288;
    int*      pos_inv  = (int*)(ws + off);      off += 524288;  // 256*2048 int
    float*    meanpart = ws + off;              off += 8192;    // 32*256
    float*    hrec     = ws + off;              off += 512;     // 2*256
    float*    crec     = ws + off;              off += 512;
    float*    rl_buf   = ws + off;              off += 2048;    // 2*1024
    float*    rl_bias  = ws + off;              off += 1024;
    ushort_t* HnewA    = (ushort_t*)(ws + off); off += 131072;  // 1024*256 u16
    ushort_t* HnewB    = (ushort_t*)(ws + off); off += 131072;
    float*    CnewA    = ws + off;              off += 262144;
    float*    CnewB    = ws + off;              off += 262144;
    ushort_t* BsatT    = (ushort_t*)(ws + off); off += 147456;  // 1024*288 u16
    float*    s2r_rwT  = ws + off;              off += 262144;
    float*    s2r_lwT  = ws + off;              off += 262144;
    float*    r2s_lwT  = ws + off;              off += 262144;

    // zero contiguous prefix: bar + Hg_bf + Cg + pos_inv
    const size_t zcount = 2560 + 262144 + 524288 + 524288;
    hipLaunchKernelGGL(k_zero, dim3(2048), dim3(256), 0, stream, ws, zcount);
    hipLaunchKernelGGL(k_bconv, dim3(9, 16), dim3(256), 0, stream, r2s_rw, W_sat, BsatT);
    hipLaunchKernelGGL(k_rlb, dim3(4), dim3(256), 0, stream, r2s_lb, b_sat, rl_bias, rl_buf);
    hipLaunchKernelGGL(k_inv, dim3(T_STEPS), dim3(256), 0, stream, s_ids, pos_inv);
    hipLaunchKernelGGL(k_wt, dim3(8, 8, 4), dim3(256), 0, stream, s2r_rw, s2r_rwT);
    hipLaunchKernelGGL(k_wt, dim3(8, 8, 4), dim3(256), 0, stream, s2r_lw, s2r_lwT);
    hipLaunchKernelGGL(k_wt, dim3(8, 8, 4), dim3(256), 0, stream, r2s_lw, r2s_lwT);

    hipLaunchKernelGGL(k_persist, dim3(NBLK_TOT), dim3(256), 0, stream,
                       x_rec, x_sat, y_true,
                       W_rec, b_rec, s2r_lb,
                       W_out, b_out,
                       s_ids, BsatT,
                       bar, Hg_bf, Cg, pos_inv,
                       meanpart, hrec, crec,
                       rl_buf, rl_bias,
                       HnewA, HnewB, CnewA, CnewB,
                       s2r_rwT, s2r_lwT, r2s_lwT,
                       (float*)d_out);
}

// Round 6
// 8020.715 us; speedup vs baseline: 2.4290x; 1.6781x over previous
//
#include <hip/hip_runtime.h>
#include <cstddef>

#define T_STEPS  256
#define NSAT     1024
#define GSAT     2048
#define HID      256
#define IN_DIM   32
#define KTOT     288   // HID + IN_DIM

typedef short  s16x8 __attribute__((ext_vector_type(8)));
typedef short  s16x4 __attribute__((ext_vector_type(4)));
typedef float  f32x4 __attribute__((ext_vector_type(4)));
typedef unsigned short ushort_t;

__device__ inline ushort_t f2bf(float f) {
    unsigned u = __builtin_bit_cast(unsigned, f);
    u += 0x7fffu + ((u >> 16) & 1u);
    return (ushort_t)(u >> 16);
}
__device__ inline float bf2f(ushort_t h) {
    unsigned u = ((unsigned)h) << 16;
    return __builtin_bit_cast(float, u);
}
__device__ inline float sigm(float x) { return 1.f / (1.f + __expf(-x)); }
__device__ inline float tanh_(float x) {
    float a = fabsf(x);
    float e = __expf(-2.f * a);
    float r = (1.f - e) / (1.f + e);
    return copysignf(r, x);
}

// ---------------- init: zero prefix ----------------
__global__ void k_zero(float* p, size_t n) {
    size_t i = (size_t)blockIdx.x * blockDim.x + threadIdx.x;
    size_t stride = (size_t)gridDim.x * blockDim.x;
    for (; i < n; i += stride) p[i] = 0.f;
}

// col order: c = (o>>3)*32 + g*8 + (o&7)  <->  g=(c>>3)&3, o=(c>>5)*8+(c&7)
__global__ void k_bconv(const float* __restrict__ r2s_rw,
                        const float* __restrict__ W_sat,
                        ushort_t* __restrict__ BsatT) {
    int c = blockIdx.x;
    int g = (c >> 3) & 3, o = (c >> 5) * 8 + (c & 7);
    for (int k = threadIdx.x; k < KTOT; k += 256) {
        float v = (k < 256) ? r2s_rw[((size_t)g * 256 + k) * 256 + o]
                            : W_sat[((size_t)g * 32 + (k - 256)) * 256 + o];
        BsatT[(size_t)c * KTOT + k] = f2bf(v);
    }
}

__global__ void k_rlw(const float* __restrict__ r2s_lw, ushort_t* __restrict__ rlw_bf) {
    int c = blockIdx.x;
    int g = (c >> 3) & 3, o = (c >> 5) * 8 + (c & 7);
    int h = threadIdx.x;
    rlw_bf[(size_t)c * 256 + h] = f2bf(r2s_lw[((size_t)g * 256 + h) * 256 + o]);
}

__global__ void k_biasC(const float* __restrict__ r2s_lb, const float* __restrict__ b_sat,
                        float* __restrict__ biasC) {
    int c = blockIdx.x * 256 + threadIdx.x;
    if (c < 1024) {
        int g = (c >> 3) & 3, o = (c >> 5) * 8 + (c & 7);
        biasC[c] = r2s_lb[g * 256 + o] + b_sat[g * 256 + o];
    }
}

__global__ void k_inv(const int* __restrict__ s_ids, int* __restrict__ pos_inv) {
    int t = blockIdx.x;
    for (int n = threadIdx.x; n < NSAT; n += 256)
        pos_inv[(size_t)t * GSAT + s_ids[(size_t)t * NSAT + n]] = n + 1;
}

// transpose [4][256][256] (g,h,o) -> (g,o,h)
__global__ void k_wt(const float* __restrict__ in, float* __restrict__ outT) {
    __shared__ float tl[32][33];
    int g = blockIdx.z;
    int h0 = blockIdx.x * 32, o0 = blockIdx.y * 32;
    int lx = threadIdx.x & 31, ly = threadIdx.x >> 5;
#pragma unroll
    for (int i = 0; i < 32; i += 8)
        tl[ly + i][lx] = in[((size_t)g * 256 + h0 + ly + i) * 256 + o0 + lx];
    __syncthreads();
#pragma unroll
    for (int i = 0; i < 32; i += 8)
        outT[((size_t)g * 256 + o0 + ly + i) * 256 + h0 + lx] = tl[lx][ly + i];
}

// W_recT[(g*256+o)*32+i] = W_rec[(g*32+i)*256+o]
__global__ void k_wrt(const float* __restrict__ W_rec, float* __restrict__ W_recT) {
    int idx = blockIdx.x * 256 + threadIdx.x;   // 0..1023 = g*256+o
    int g = idx >> 8, o = idx & 255;
#pragma unroll
    for (int i = 0; i < 32; i++)
        W_recT[(size_t)idx * 32 + i] = W_rec[((size_t)g * 32 + i) * 256 + o];
}

// ---------------- per-step kernel: grid 288 (32 rec + 256 sat) ----------------
__launch_bounds__(256)
__global__ void k_step(int t,
    const float* __restrict__ x_rec, const float* __restrict__ x_sat,
    const float* __restrict__ b_rec, const float* __restrict__ s2r_lb,
    const int* __restrict__ s_ids, const int* __restrict__ pos_inv,
    const ushort_t* __restrict__ BsatT, const ushort_t* __restrict__ rlw_bf,
    const float* __restrict__ biasC,
    const float* __restrict__ s2r_rwT, const float* __restrict__ s2r_lwT,
    const float* __restrict__ W_recT,
    unsigned* __restrict__ flags, float* __restrict__ meanpart,
    float* __restrict__ h_rec, float* __restrict__ crec,
    ushort_t* __restrict__ Hg_bf, float* __restrict__ Cg,
    const ushort_t* __restrict__ HnP, ushort_t* __restrict__ HnC,
    const float* __restrict__ CnP, float* __restrict__ CnC)
{
    const int b = blockIdx.x, tid = threadIdx.x;

    if (b < 32) {
        // ========== receiver blocks: mean -> rec LSTM -> publish h_rec(t) ==========
        const int r = b;
        __shared__ float mh_s[HID], hr_s[HID], xr_s[IN_DIM], pre4[4][8];
        // wait for the 8 mean-partial flags (one-way; writers never wait -> no deadlock)
        if (tid < 8) {
            while (__hip_atomic_load(&flags[tid * 32], __ATOMIC_ACQUIRE, __HIP_MEMORY_SCOPE_AGENT)
                   < (unsigned)(t + 1))
                __builtin_amdgcn_s_sleep(1);
        }
        __syncthreads();
        __threadfence();
        float mh = 0.f;
#pragma unroll
        for (int p = 0; p < 8; p++) mh += meanpart[p * HID + tid];
        mh_s[tid] = mh * (1.f / 1024.f);
        hr_s[tid] = h_rec[((t + 1) & 1) * HID + tid];   // h_rec(t-1)
        if (tid < IN_DIM) xr_s[tid] = x_rec[(size_t)t * IN_DIM + tid];
        __syncthreads();
        {
            const int combo = tid >> 3, sub = tid & 7;
            const int g = combo >> 3, oo = combo & 7;
            const int o = r * 8 + oo;
            const float* rwp = s2r_rwT + ((size_t)(g * 256 + o)) * 256 + sub * 32;
            const float* lwp = s2r_lwT + ((size_t)(g * 256 + o)) * 256 + sub * 32;
            float part = 0.f;
#pragma unroll
            for (int q = 0; q < 8; q++) {
                f32x4 a = *(const f32x4*)(rwp + q * 4);
                f32x4 c = *(const f32x4*)(lwp + q * 4);
#pragma unroll
                for (int e = 0; e < 4; e++) {
                    int h = sub * 32 + q * 4 + e;
                    part += hr_s[h] * a[e] + mh_s[h] * c[e];
                }
            }
            {
                f32x4 wx = *(const f32x4*)(W_recT + ((size_t)(g * 256 + o)) * 32 + sub * 4);
#pragma unroll
                for (int e = 0; e < 4; e++) part += xr_s[sub * 4 + e] * wx[e];
            }
            part += __shfl_down(part, 4);
            part += __shfl_down(part, 2);
            part += __shfl_down(part, 1);
            if (sub == 0) pre4[g][oo] = part + b_rec[g * HID + o] + s2r_lb[g * HID + o];
        }
        __syncthreads();
        if (tid < 8) {
            int o = r * 8 + tid;
            float pi = pre4[0][tid], pf = pre4[1][tid], pc = pre4[2][tid], po = pre4[3][tid];
            float cp = crec[o];
            float ig = sigm(pi), fg = sigm(pf), tg = tanh_(pc), og = sigm(po);
            float cn = fg * cp + ig * tg;
            crec[o] = cn;
            h_rec[(t & 1) * HID + o] = og * tanh_(cn);   // consumed next launch
        }
    } else {
        // ========== satellite blocks: rl + GEMM + LSTM epilogue + scatter ==========
        const int s = b - 32;
        const int by = s >> 5;     // row-group (128 rows)
        const int bxc = s & 31;    // col-group (8 outs x 4 gates)
        __shared__ int   sid_s[128], src_s[128];
        __shared__ float hr_s[HID];
        __shared__ float rl_s[32];
        __shared__ float pre_s[128][33];

        if (tid < 128) {
            int j = s_ids[(size_t)t * NSAT + by * 128 + tid];
            sid_s[tid] = j;
            src_s[tid] = (t > 0) ? pos_inv[(size_t)(t - 1) * GSAT + j] - 1 : -1;
        }
        hr_s[tid] = h_rec[((t + 1) & 1) * HID + tid];   // h_rec(t-1), prev launch
        __syncthreads();

        // --- rl slice: r2s_lw^T . h_rec(t-1) + (r2s_lb + b_sat), 32 cols ---
        {
            int c = tid >> 3, sub = tid & 7;
            const ushort_t* wp = rlw_bf + ((size_t)(bxc * 32 + c)) * 256 + sub * 32;
            float acc = 0.f;
#pragma unroll
            for (int q = 0; q < 4; q++) {
                s16x8 wv = *(const s16x8*)(wp + q * 8);
#pragma unroll
                for (int e = 0; e < 8; e++)
                    acc += hr_s[sub * 32 + q * 8 + e] * bf2f((ushort_t)wv[e]);
            }
            acc += __shfl_down(acc, 4);
            acc += __shfl_down(acc, 2);
            acc += __shfl_down(acc, 1);
            if (sub == 0) rl_s[c] = acc + biasC[bxc * 32 + c];
        }

        // --- mean partial (col-group 0 only) + release flag ---
        if (bxc == 0) {
            float m = 0.f;
            for (int n = 0; n < 128; n++) {
                int p = src_s[n];
                const ushort_t* hp = (p >= 0) ? HnP + (size_t)p * HID
                                              : Hg_bf + (size_t)sid_s[n] * HID;
                m += bf2f(hp[tid]);
            }
            meanpart[by * HID + tid] = m;
            __syncthreads();
            if (tid == 0) {
                __threadfence();
                __hip_atomic_store(&flags[by * 32], (unsigned)(t + 1),
                                   __ATOMIC_RELEASE, __HIP_MEMORY_SCOPE_AGENT);
            }
        }

        // --- MFMA GEMM: 128 rows x 32 cols, K = 256(h) + 32(x) ---
        const int w = tid >> 6, l = tid & 63;
        const int lr = l & 15, kb = (l >> 4) * 8;
        const int r0 = w * 32 + lr, r1 = r0 + 16;
        const int p0 = src_s[r0], p1 = src_s[r1];
        const ushort_t* a0 = (p0 >= 0) ? HnP + (size_t)p0 * HID : Hg_bf + (size_t)sid_s[r0] * HID;
        const ushort_t* a1 = (p1 >= 0) ? HnP + (size_t)p1 * HID : Hg_bf + (size_t)sid_s[r1] * HID;
        const ushort_t* bp0 = BsatT + ((size_t)(bxc * 32 + lr)) * KTOT;
        const ushort_t* bp1 = BsatT + ((size_t)(bxc * 32 + 16 + lr)) * KTOT;
        f32x4 a00 = {0.f,0.f,0.f,0.f}, a01 = a00, a10 = a00, a11 = a00;
#pragma unroll
        for (int kc = 0; kc < 8; kc++) {
            int k0 = kc * 32 + kb;
            s16x8 af0 = *(const s16x8*)(a0 + k0);
            s16x8 af1 = *(const s16x8*)(a1 + k0);
            s16x8 bv0 = *(const s16x8*)(bp0 + k0);
            s16x8 bv1 = *(const s16x8*)(bp1 + k0);
            a00 = __builtin_amdgcn_mfma_f32_16x16x32_bf16(af0, bv0, a00, 0, 0, 0);
            a01 = __builtin_amdgcn_mfma_f32_16x16x32_bf16(af0, bv1, a01, 0, 0, 0);
            a10 = __builtin_amdgcn_mfma_f32_16x16x32_bf16(af1, bv0, a10, 0, 0, 0);
            a11 = __builtin_amdgcn_mfma_f32_16x16x32_bf16(af1, bv1, a11, 0, 0, 0);
        }
        {   // x tail (K = 256..287)
            const float* ax0 = x_sat + ((size_t)t * NSAT + by * 128 + r0) * IN_DIM + kb;
            const float* ax1 = x_sat + ((size_t)t * NSAT + by * 128 + r1) * IN_DIM + kb;
            f32x4 x00 = *(const f32x4*)ax0, x01 = *(const f32x4*)(ax0 + 4);
            f32x4 x10 = *(const f32x4*)ax1, x11 = *(const f32x4*)(ax1 + 4);
            s16x8 af0, af1;
#pragma unroll
            for (int e = 0; e < 4; e++) {
                af0[e] = (short)f2bf(x00[e]); af0[4 + e] = (short)f2bf(x01[e]);
                af1[e] = (short)f2bf(x10[e]); af1[4 + e] = (short)f2bf(x11[e]);
            }
            int k0 = 256 + kb;
            s16x8 bv0 = *(const s16x8*)(bp0 + k0);
            s16x8 bv1 = *(const s16x8*)(bp1 + k0);
            a00 = __builtin_amdgcn_mfma_f32_16x16x32_bf16(af0, bv0, a00, 0, 0, 0);
            a01 = __builtin_amdgcn_mfma_f32_16x16x32_bf16(af0, bv1, a01, 0, 0, 0);
            a10 = __builtin_amdgcn_mfma_f32_16x16x32_bf16(af1, bv0, a10, 0, 0, 0);
            a11 = __builtin_amdgcn_mfma_f32_16x16x32_bf16(af1, bv1, a11, 0, 0, 0);
        }
        // stage C (col=lane&15, row=(lane>>4)*4+reg)
#pragma unroll
        for (int rr = 0; rr < 4; rr++) {
            int ro = (l >> 4) * 4 + rr;
            pre_s[w * 32 + ro][lr]           = a00[rr];
            pre_s[w * 32 + ro][16 + lr]      = a01[rr];
            pre_s[w * 32 + 16 + ro][lr]      = a10[rr];
            pre_s[w * 32 + 16 + ro][16 + lr] = a11[rr];
        }
        __syncthreads();

        // --- epilogue: LSTM over 4 cells/thread, write HnC/CnC ---
        {
            int n = tid >> 1, oi0 = (tid & 1) * 4;
            int og0 = bxc * 8 + oi0;
            int pn = src_s[n], j = sid_s[n];
            const float* csrc = (pn >= 0) ? CnP + (size_t)pn * HID + og0
                                          : Cg + (size_t)j * HID + og0;
            f32x4 cold = *(const f32x4*)csrc;
            f32x4 cnew; s16x4 hnew;
#pragma unroll
            for (int e = 0; e < 4; e++) {
                int oi = oi0 + e;
                float pi = pre_s[n][0 * 8 + oi] + rl_s[0 * 8 + oi];
                float pf = pre_s[n][1 * 8 + oi] + rl_s[1 * 8 + oi];
                float pc = pre_s[n][2 * 8 + oi] + rl_s[2 * 8 + oi];
                float po = pre_s[n][3 * 8 + oi] + rl_s[3 * 8 + oi];
                float ig = sigm(pi), fg = sigm(pf), tg = tanh_(pc), oo = sigm(po);
                float cn = fg * cold[e] + ig * tg;
                cnew[e] = cn;
                hnew[e] = (short)f2bf(oo * tanh_(cn));
            }
            size_t gr = (size_t)(by * 128 + n);
            *(f32x4*)(CnC + gr * HID + og0) = cnew;
            *(s16x4*)(HnC + gr * HID + og0) = hnew;
        }

        // --- deferred scatter of step t-1 (rows disjoint from all step-t reads) ---
        if (t > 0) {
#pragma unroll
            for (int i = 0; i < 4; i++) {
                int n = s * 4 + i;
                int j = s_ids[(size_t)(t - 1) * NSAT + n];
                Hg_bf[(size_t)j * HID + tid] = HnP[(size_t)n * HID + tid];
                Cg[(size_t)j * HID + tid]    = CnP[(size_t)n * HID + tid];
            }
        }
    }
}

// ---------------- final: output projection ----------------
__global__ void k_final(const float* __restrict__ h_rec,
                        const float* __restrict__ W_out,
                        const float* __restrict__ b_out,
                        const float* __restrict__ y_true,
                        float* __restrict__ out) {
    __shared__ float red[256];
    int o = threadIdx.x;
    float h = h_rec[((T_STEPS - 1) & 1) * HID + o];
    for (int j = 0; j < 2; j++) {
        red[o] = h * W_out[o * 2 + j];
        __syncthreads();
        for (int s = 128; s > 0; s >>= 1) {
            if (o < s) red[o] += red[o + s];
            __syncthreads();
        }
        if (o == 0) out[j] = red[0] + b_out[j];
        __syncthreads();
    }
    if (o < 2) out[2 + o] = y_true[o];
}

extern "C" void kernel_launch(void* const* d_in, const int* in_sizes, int n_in,
                              void* d_out, int out_size, void* d_ws, size_t ws_size,
                              hipStream_t stream) {
    (void)in_sizes; (void)n_in; (void)out_size; (void)ws_size;
    const float* x_rec  = (const float*)d_in[0];
    const float* x_sat  = (const float*)d_in[1];
    const float* y_true = (const float*)d_in[2];
    const float* W_rec  = (const float*)d_in[3];
    const float* b_rec  = (const float*)d_in[4];
    const float* W_sat  = (const float*)d_in[5];
    const float* b_sat  = (const float*)d_in[6];
    const float* s2r_lw = (const float*)d_in[7];
    const float* s2r_lb = (const float*)d_in[8];
    const float* s2r_rw = (const float*)d_in[9];
    const float* r2s_lw = (const float*)d_in[10];
    const float* r2s_lb = (const float*)d_in[11];
    const float* r2s_rw = (const float*)d_in[12];
    const float* W_out  = (const float*)d_in[13];
    const float* b_out  = (const float*)d_in[14];
    const int*   s_ids  = (const int*)d_in[15];

    float* ws = (float*)d_ws;
    size_t off = 0;
    unsigned* flags    = (unsigned*)(ws + off); off += 512;     // 8 padded lines
    float*    meanpart = ws + off;              off += 2048;    // 8*256
    float*    h_rec    = ws + off;              off += 512;     // 2*256
    float*    crec     = ws + off;              off += 256;
    ushort_t* Hg_bf    = (ushort_t*)(ws + off); off += 262144;  // 2048*256 u16
    float*    Cg       = ws + off;              off += 524288;
    int*      pos_inv  = (int*)(ws + off);      off += 524288;
    ushort_t* HnewA    = (ushort_t*)(ws + off); off += 131072;  // 1024*256 u16
    ushort_t* HnewB    = (ushort_t*)(ws + off); off += 131072;
    float*    CnewA    = ws + off;              off += 262144;
    float*    CnewB    = ws + off;              off += 262144;
    ushort_t* BsatT    = (ushort_t*)(ws + off); off += 147456;  // 1024*288 u16
    ushort_t* rlw_bf   = (ushort_t*)(ws + off); off += 131072;  // 1024*256 u16
    float*    biasC    = ws + off;              off += 1024;
    float*    s2r_rwT  = ws + off;              off += 262144;
    float*    s2r_lwT  = ws + off;              off += 262144;
    float*    W_recT   = ws + off;              off += 32768;   // 4*256*32

    // zero prefix: flags + meanpart + h_rec + crec + Hg_bf + Cg
    const size_t zcount = 512 + 2048 + 512 + 256 + 262144 + 524288;
    hipLaunchKernelGGL(k_zero, dim3(2048), dim3(256), 0, stream, ws, zcount);
    hipLaunchKernelGGL(k_bconv, dim3(1024), dim3(256), 0, stream, r2s_rw, W_sat, BsatT);
    hipLaunchKernelGGL(k_rlw, dim3(1024), dim3(256), 0, stream, r2s_lw, rlw_bf);
    hipLaunchKernelGGL(k_biasC, dim3(4), dim3(256), 0, stream, r2s_lb, b_sat, biasC);
    hipLaunchKernelGGL(k_inv, dim3(T_STEPS), dim3(256), 0, stream, s_ids, pos_inv);
    hipLaunchKernelGGL(k_wt, dim3(8, 8, 4), dim3(256), 0, stream, s2r_rw, s2r_rwT);
    hipLaunchKernelGGL(k_wt, dim3(8, 8, 4), dim3(256), 0, stream, s2r_lw, s2r_lwT);
    hipLaunchKernelGGL(k_wrt, dim3(4), dim3(256), 0, stream, W_rec, W_recT);

    for (int t = 0; t < T_STEPS; t++) {
        // t even: read B-bufs (prev), write A-bufs. t odd: read A, write B.
        const ushort_t* HnP = (t & 1) ? HnewA : HnewB;
        ushort_t*       HnC = (t & 1) ? HnewB : HnewA;
        const float*    CnP = (t & 1) ? CnewA : CnewB;
        float*          CnC = (t & 1) ? CnewB : CnewA;
        hipLaunchKernelGGL(k_step, dim3(288), dim3(256), 0, stream,
                           t, x_rec, x_sat, b_rec, s2r_lb,
                           s_ids, pos_inv, BsatT, rlw_bf, biasC,
                           s2r_rwT, s2r_lwT, W_recT,
                           flags, meanpart, h_rec, crec,
                           Hg_bf, Cg, HnP, HnC, CnP, CnC);
    }
    hipLaunchKernelGGL(k_final, dim3(1), dim3(256), 0, stream,
                       h_rec, W_out, b_out, y_true, (float*)d_out);
}

// Round 7
// 5310.800 us; speedup vs baseline: 3.6684x; 1.5103x over previous
//
#include <hip/hip_runtime.h>
#include <cstddef>

#define T_STEPS  256
#define NSAT     1024
#define GSAT     2048
#define HID      256
#define IN_DIM   32
#define KTOT     544   // 256 h_sat + 32 x_sat + 256 h_rec (rl folded into GEMM)

typedef short  s16x8 __attribute__((ext_vector_type(8)));
typedef short  s16x4 __attribute__((ext_vector_type(4)));
typedef float  f32x4 __attribute__((ext_vector_type(4)));
typedef unsigned short ushort_t;

__device__ inline ushort_t f2bf(float f) {
    unsigned u = __builtin_bit_cast(unsigned, f);
    u += 0x7fffu + ((u >> 16) & 1u);
    return (ushort_t)(u >> 16);
}
__device__ inline float bf2f(ushort_t h) {
    unsigned u = ((unsigned)h) << 16;
    return __builtin_bit_cast(float, u);
}
__device__ inline float sigm(float x) { return 1.f / (1.f + __expf(-x)); }
__device__ inline float tanh_(float x) {
    float a = fabsf(x);
    float e = __expf(-2.f * a);
    float r = (1.f - e) / (1.f + e);
    return copysignf(r, x);
}

// ---------------- init: zero prefix ----------------
__global__ void k_zero(float* p, size_t n) {
    size_t i = (size_t)blockIdx.x * blockDim.x + threadIdx.x;
    size_t stride = (size_t)gridDim.x * blockDim.x;
    for (; i < n; i += stride) p[i] = 0.f;
}

// col order: c = (o>>3)*32 + g*8 + (o&7)  <->  g=(c>>3)&3, o=(c>>5)*8+(c&7)
// B row c, k<256: r2s_rw ; k<288: W_sat ; else: r2s_lw (rl fold)
__global__ void k_bconv(const float* __restrict__ r2s_rw,
                        const float* __restrict__ W_sat,
                        const float* __restrict__ r2s_lw,
                        ushort_t* __restrict__ BsatT) {
    int c = blockIdx.x;
    int g = (c >> 3) & 3, o = (c >> 5) * 8 + (c & 7);
    for (int k = threadIdx.x; k < KTOT; k += 256) {
        float v;
        if (k < 256)      v = r2s_rw[((size_t)g * 256 + k) * 256 + o];
        else if (k < 288) v = W_sat[((size_t)g * 32 + (k - 256)) * 256 + o];
        else              v = r2s_lw[((size_t)g * 256 + (k - 288)) * 256 + o];
        BsatT[(size_t)c * KTOT + k] = f2bf(v);
    }
}

__global__ void k_biasC(const float* __restrict__ r2s_lb, const float* __restrict__ b_sat,
                        float* __restrict__ biasC) {
    int c = blockIdx.x * 256 + threadIdx.x;
    if (c < 1024) {
        int g = (c >> 3) & 3, o = (c >> 5) * 8 + (c & 7);
        biasC[c] = r2s_lb[g * 256 + o] + b_sat[g * 256 + o];
    }
}

__global__ void k_inv(const int* __restrict__ s_ids, ushort_t* __restrict__ pos_inv) {
    int t = blockIdx.x;
    for (int n = threadIdx.x; n < NSAT; n += 256)
        pos_inv[(size_t)t * GSAT + s_ids[(size_t)t * NSAT + n]] = (ushort_t)(n + 1);
}

// transpose [4][256][256] (g,h,o) -> (g,o,h), bf16 output
__global__ void k_wtb(const float* __restrict__ in, ushort_t* __restrict__ outT) {
    __shared__ float tl[32][33];
    int g = blockIdx.z;
    int h0 = blockIdx.x * 32, o0 = blockIdx.y * 32;
    int lx = threadIdx.x & 31, ly = threadIdx.x >> 5;
#pragma unroll
    for (int i = 0; i < 32; i += 8)
        tl[ly + i][lx] = in[((size_t)g * 256 + h0 + ly + i) * 256 + o0 + lx];
    __syncthreads();
#pragma unroll
    for (int i = 0; i < 32; i += 8)
        outT[((size_t)g * 256 + o0 + ly + i) * 256 + h0 + lx] = f2bf(tl[lx][ly + i]);
}

// W_recT[(g*256+o)*32+i] = W_rec[(g*32+i)*256+o]
__global__ void k_wrt(const float* __restrict__ W_rec, float* __restrict__ W_recT) {
    int idx = blockIdx.x * 256 + threadIdx.x;
    int g = idx >> 8, o = idx & 255;
#pragma unroll
    for (int i = 0; i < 32; i++)
        W_recT[(size_t)idx * 32 + i] = W_rec[((size_t)g * 32 + i) * 256 + o];
}

// ---------------- per-step kernel: grid 288 (256 sat + 32 rec), NO cross-block waits
__launch_bounds__(256)
__global__ void k_step(int t,
    const float* __restrict__ x_rec, const float* __restrict__ x_sat,
    const float* __restrict__ b_rec, const float* __restrict__ s2r_lb,
    const int* __restrict__ s_ids, const ushort_t* __restrict__ pos_inv,
    const ushort_t* __restrict__ BsatT, const float* __restrict__ biasC,
    const ushort_t* __restrict__ s2r_rwT, const ushort_t* __restrict__ s2r_lwT,
    const float* __restrict__ W_recT,
    float* __restrict__ meanN,    // [2][8*256]
    float* __restrict__ oldpart,  // [2][32*256]
    float* __restrict__ crec,     // [2][256]
    float* __restrict__ pre_rec,  // [2][1024]
    ushort_t* __restrict__ Hg_bf, float* __restrict__ Cg,
    const ushort_t* __restrict__ HnP, ushort_t* __restrict__ HnC,
    const float* __restrict__ CnP, float* __restrict__ CnC)
{
    const int b = blockIdx.x, tid = threadIdx.x;
    const float* preP  = pre_rec + ((t + 1) & 1) * 1024;  // pre_rec(t-1)
    const float* crecP = crec + (t & 1) * 256;            // crec(t-2)

    if (b < 256) {
        // ================= satellite block: by row-group, bxc col-group =========
        const int by = b >> 5, bxc = b & 31;
        __shared__ int      sid_s[128], src_s[128];
        __shared__ ushort_t hr_bfs[256];
        __shared__ float    bias_s[32];
        __shared__ float    pre_s[128][33];

        if (tid < 128) {
            int j = s_ids[(size_t)t * NSAT + by * 128 + tid];
            sid_s[tid] = j;
            src_s[tid] = (t > 0) ? (int)pos_inv[(size_t)(t - 1) * GSAT + j] - 1 : -1;
        }
        if (tid < 32) bias_s[tid] = biasC[bxc * 32 + tid];
        {   // redundant elementwise h_rec(t-1) from pre_rec(t-1), crec(t-2)
            float h = 0.f;
            if (t > 0) {
                float pi = preP[tid], pf = preP[256 + tid], pc = preP[512 + tid], po = preP[768 + tid];
                float cp = (t >= 2) ? crecP[tid] : 0.f;
                float cn = sigm(pf) * cp + sigm(pi) * tanh_(pc);
                h = sigm(po) * tanh_(cn);
            }
            hr_bfs[tid] = f2bf(h);
        }
        __syncthreads();

        // --- MFMA GEMM: 128 rows x 32 gate-cols, K = 256(h) + 32(x) + 256(h_rec) ---
        const int w = tid >> 6, l = tid & 63;
        const int lr = l & 15, kb = (l >> 4) * 8;
        const int r0 = w * 32 + lr, r1 = r0 + 16;
        const int p0 = src_s[r0], p1 = src_s[r1];
        const ushort_t* a0 = (p0 >= 0) ? HnP + (size_t)p0 * HID : Hg_bf + (size_t)sid_s[r0] * HID;
        const ushort_t* a1 = (p1 >= 0) ? HnP + (size_t)p1 * HID : Hg_bf + (size_t)sid_s[r1] * HID;
        const ushort_t* bp0 = BsatT + ((size_t)(bxc * 32 + lr)) * KTOT;
        const ushort_t* bp1 = bp0 + (size_t)16 * KTOT;
        f32x4 a00 = {0.f,0.f,0.f,0.f}, a01 = a00, a10 = a00, a11 = a00;
#pragma unroll
        for (int kc = 0; kc < 8; kc++) {
            int k0 = kc * 32 + kb;
            s16x8 af0 = *(const s16x8*)(a0 + k0);
            s16x8 af1 = *(const s16x8*)(a1 + k0);
            s16x8 bv0 = *(const s16x8*)(bp0 + k0);
            s16x8 bv1 = *(const s16x8*)(bp1 + k0);
            a00 = __builtin_amdgcn_mfma_f32_16x16x32_bf16(af0, bv0, a00, 0, 0, 0);
            a01 = __builtin_amdgcn_mfma_f32_16x16x32_bf16(af0, bv1, a01, 0, 0, 0);
            a10 = __builtin_amdgcn_mfma_f32_16x16x32_bf16(af1, bv0, a10, 0, 0, 0);
            a11 = __builtin_amdgcn_mfma_f32_16x16x32_bf16(af1, bv1, a11, 0, 0, 0);
        }
        {   // x segment (K = 256..287)
            const float* ax0 = x_sat + ((size_t)t * NSAT + by * 128 + r0) * IN_DIM + kb;
            const float* ax1 = x_sat + ((size_t)t * NSAT + by * 128 + r1) * IN_DIM + kb;
            f32x4 x00 = *(const f32x4*)ax0, x01 = *(const f32x4*)(ax0 + 4);
            f32x4 x10 = *(const f32x4*)ax1, x11 = *(const f32x4*)(ax1 + 4);
            s16x8 af0, af1;
#pragma unroll
            for (int e = 0; e < 4; e++) {
                af0[e] = (short)f2bf(x00[e]); af0[4 + e] = (short)f2bf(x01[e]);
                af1[e] = (short)f2bf(x10[e]); af1[4 + e] = (short)f2bf(x11[e]);
            }
            int k0 = 256 + kb;
            s16x8 bv0 = *(const s16x8*)(bp0 + k0);
            s16x8 bv1 = *(const s16x8*)(bp1 + k0);
            a00 = __builtin_amdgcn_mfma_f32_16x16x32_bf16(af0, bv0, a00, 0, 0, 0);
            a01 = __builtin_amdgcn_mfma_f32_16x16x32_bf16(af0, bv1, a01, 0, 0, 0);
            a10 = __builtin_amdgcn_mfma_f32_16x16x32_bf16(af1, bv0, a10, 0, 0, 0);
            a11 = __builtin_amdgcn_mfma_f32_16x16x32_bf16(af1, bv1, a11, 0, 0, 0);
        }
#pragma unroll
        for (int kc = 0; kc < 8; kc++) {   // h_rec segment (K = 288..543), A uniform
            int k0 = 288 + kc * 32 + kb;
            s16x8 af = *(const s16x8*)(hr_bfs + (k0 - 288));
            s16x8 bv0 = *(const s16x8*)(bp0 + k0);
            s16x8 bv1 = *(const s16x8*)(bp1 + k0);
            a00 = __builtin_amdgcn_mfma_f32_16x16x32_bf16(af, bv0, a00, 0, 0, 0);
            a01 = __builtin_amdgcn_mfma_f32_16x16x32_bf16(af, bv1, a01, 0, 0, 0);
            a10 = __builtin_amdgcn_mfma_f32_16x16x32_bf16(af, bv0, a10, 0, 0, 0);
            a11 = __builtin_amdgcn_mfma_f32_16x16x32_bf16(af, bv1, a11, 0, 0, 0);
        }
        // stage C (col=lane&15, row=(lane>>4)*4+reg)
#pragma unroll
        for (int rr = 0; rr < 4; rr++) {
            int ro = (l >> 4) * 4 + rr;
            pre_s[w * 32 + ro][lr]           = a00[rr];
            pre_s[w * 32 + ro][16 + lr]      = a01[rr];
            pre_s[w * 32 + 16 + ro][lr]      = a10[rr];
            pre_s[w * 32 + 16 + ro][16 + lr] = a11[rr];
        }
        __syncthreads();

        // --- epilogue: LSTM over 4 cells/thread, write HnC/CnC + meanN staging ---
        {
            int n = tid >> 1, oi0 = (tid & 1) * 4;
            int og0 = bxc * 8 + oi0;
            int pn = src_s[n], j = sid_s[n];
            const float* csrc = (pn >= 0) ? CnP + (size_t)pn * HID + og0
                                          : Cg + (size_t)j * HID + og0;
            f32x4 cold = *(const f32x4*)csrc;
            f32x4 cnew, hf; s16x4 hnew;
#pragma unroll
            for (int e = 0; e < 4; e++) {
                int oi = oi0 + e;
                float pi = pre_s[n][oi]      + bias_s[oi];
                float pf = pre_s[n][8 + oi]  + bias_s[8 + oi];
                float pc = pre_s[n][16 + oi] + bias_s[16 + oi];
                float po = pre_s[n][24 + oi] + bias_s[24 + oi];
                float ig = sigm(pi), fg = sigm(pf), tg = tanh_(pc), oo = sigm(po);
                float cn = fg * cold[e] + ig * tg;
                float hn = oo * tanh_(cn);
                cnew[e] = cn; hf[e] = hn;
                hnew[e] = (short)f2bf(hn);
            }
            size_t gr = (size_t)(by * 128 + n);
            *(f32x4*)(CnC + gr * HID + og0) = cnew;
            *(s16x4*)(HnC + gr * HID + og0) = hnew;
            // meanN(t+1) staging: masked hnew (same-thread LDS cells; reads above done)
            bool nxt = (t + 1 < T_STEPS) && (pos_inv[(size_t)(t + 1) * GSAT + j] > 0);
#pragma unroll
            for (int e = 0; e < 4; e++) pre_s[n][oi0 + e] = nxt ? hf[e] : 0.f;
        }
        __syncthreads();
        if (t + 1 < T_STEPS && tid < 8) {
            float s = 0.f;
            for (int n = 0; n < 128; n++) s += pre_s[n][tid];
            meanN[((t + 1) & 1) * 2048 + by * 256 + bxc * 8 + tid] = s;
        }

        // --- deferred scatter of step t-1 (rows disjoint from all step-t reads) ---
        if (t > 0) {
#pragma unroll
            for (int i = 0; i < 4; i++) {
                int n = b * 4 + i;
                int j = s_ids[(size_t)(t - 1) * NSAT + n];
                Hg_bf[(size_t)j * HID + tid] = HnP[(size_t)n * HID + tid];
                Cg[(size_t)j * HID + tid]    = CnP[(size_t)n * HID + tid];
            }
        }
    } else {
        // ================= rec block r: mean reduce -> pre_rec(t) -> oldpart(t+1) ==
        const int r = b - 256;
        __shared__ float mean_s[256], hr_s[256], xr_s[32];
        {   // reduce mean(t) from prev-launch partials
            float s = 0.f;
            const float* mp = meanN + (t & 1) * 2048;
#pragma unroll
            for (int p = 0; p < 8; p++) s += mp[p * 256 + tid];
            const float* op = oldpart + (t & 1) * 8192;
#pragma unroll 8
            for (int p = 0; p < 32; p++) s += op[p * 256 + tid];
            mean_s[tid] = s * (1.f / 1024.f);
        }
        {   // elementwise h_rec(t-1); block r==0 stores crec(t-1)
            float h = 0.f, cn = 0.f;
            if (t > 0) {
                float pi = preP[tid], pf = preP[256 + tid], pc = preP[512 + tid], po = preP[768 + tid];
                float cp = (t >= 2) ? crecP[tid] : 0.f;
                cn = sigm(pf) * cp + sigm(pi) * tanh_(pc);
                h = sigm(po) * tanh_(cn);
            }
            hr_s[tid] = h;
            if (r == 0 && t > 0) crec[((t + 1) & 1) * 256 + tid] = cn;
        }
        if (tid < 32) xr_s[tid] = x_rec[(size_t)t * IN_DIM + tid];
        __syncthreads();
        {   // pre_rec(t) matvec: 32 gate-outs per block (bf16 weights)
            const int combo = tid >> 3, sub = tid & 7;
            const int g = combo >> 3, oo = combo & 7;
            const int o = r * 8 + oo;
            const ushort_t* rwp = s2r_rwT + ((size_t)(g * 256 + o)) * 256 + sub * 32;
            const ushort_t* lwp = s2r_lwT + ((size_t)(g * 256 + o)) * 256 + sub * 32;
            float part = 0.f;
#pragma unroll
            for (int q = 0; q < 4; q++) {
                s16x8 a = *(const s16x8*)(rwp + q * 8);
                s16x8 c = *(const s16x8*)(lwp + q * 8);
#pragma unroll
                for (int e = 0; e < 8; e++) {
                    int h = sub * 32 + q * 8 + e;
                    part += hr_s[h] * bf2f((ushort_t)a[e]) + mean_s[h] * bf2f((ushort_t)c[e]);
                }
            }
            {
                f32x4 wx = *(const f32x4*)(W_recT + ((size_t)(g * 256 + o)) * 32 + sub * 4);
#pragma unroll
                for (int e = 0; e < 4; e++) part += xr_s[sub * 4 + e] * wx[e];
            }
            part += __shfl_down(part, 4);
            part += __shfl_down(part, 2);
            part += __shfl_down(part, 1);
            if (sub == 0)
                pre_rec[(t & 1) * 1024 + g * 256 + o] =
                    part + b_rec[g * HID + o] + s2r_lb[g * HID + o];
        }
        // oldpart(t+1): rows of sids(t+1) not in sids(t), from state(t-1) view
        if (t + 1 < T_STEPS) {
            float s = 0.f;
            for (int i = 0; i < 32; i++) {
                int n2 = r * 32 + i;
                int j = s_ids[(size_t)(t + 1) * NSAT + n2];
                if (pos_inv[(size_t)t * GSAT + j] == 0) {
                    int p = (t > 0) ? (int)pos_inv[(size_t)(t - 1) * GSAT + j] - 1 : -1;
                    const ushort_t* hp = (p >= 0) ? HnP + (size_t)p * HID
                                                  : Hg_bf + (size_t)j * HID;
                    s += bf2f(hp[tid]);
                }
            }
            oldpart[((t + 1) & 1) * 8192 + r * 256 + tid] = s;
        }
    }
}

// ---------------- final: elementwise h_rec(255) + output projection ----------------
__global__ void k_final(const float* __restrict__ pre_rec,
                        const float* __restrict__ crec,
                        const float* __restrict__ W_out,
                        const float* __restrict__ b_out,
                        const float* __restrict__ y_true,
                        float* __restrict__ out) {
    __shared__ float red[256];
    int o = threadIdx.x;
    const float* pre = pre_rec + ((T_STEPS - 1) & 1) * 1024;   // pre_rec(255)
    float pi = pre[o], pf = pre[256 + o], pc = pre[512 + o], po = pre[768 + o];
    float cp = crec[(T_STEPS & 1) * 256 + o];                  // crec(254)
    float cn = sigm(pf) * cp + sigm(pi) * tanh_(pc);
    float h = sigm(po) * tanh_(cn);
    for (int j = 0; j < 2; j++) {
        red[o] = h * W_out[o * 2 + j];
        __syncthreads();
        for (int s = 128; s > 0; s >>= 1) {
            if (o < s) red[o] += red[o + s];
            __syncthreads();
        }
        if (o == 0) out[j] = red[0] + b_out[j];
        __syncthreads();
    }
    if (o < 2) out[2 + o] = y_true[o];
}

extern "C" void kernel_launch(void* const* d_in, const int* in_sizes, int n_in,
                              void* d_out, int out_size, void* d_ws, size_t ws_size,
                              hipStream_t stream) {
    (void)in_sizes; (void)n_in; (void)out_size; (void)ws_size;
    const float* x_rec  = (const float*)d_in[0];
    const float* x_sat  = (const float*)d_in[1];
    const float* y_true = (const float*)d_in[2];
    const float* W_rec  = (const float*)d_in[3];
    const float* b_rec  = (const float*)d_in[4];
    const float* W_sat  = (const float*)d_in[5];
    const float* b_sat  = (const float*)d_in[6];
    const float* s2r_lw = (const float*)d_in[7];
    const float* s2r_lb = (const float*)d_in[8];
    const float* s2r_rw = (const float*)d_in[9];
    const float* r2s_lw = (const float*)d_in[10];
    const float* r2s_lb = (const float*)d_in[11];
    const float* r2s_rw = (const float*)d_in[12];
    const float* W_out  = (const float*)d_in[13];
    const float* b_out  = (const float*)d_in[14];
    const int*   s_ids  = (const int*)d_in[15];

    float* ws = (float*)d_ws;
    size_t off = 0;
    float*    meanN    = ws + off;              off += 4096;    // [2][8*256]
    float*    oldpart  = ws + off;              off += 16384;   // [2][32*256]
    float*    crec     = ws + off;              off += 512;     // [2][256]
    float*    pre_rec  = ws + off;              off += 2048;    // [2][1024]
    ushort_t* Hg_bf    = (ushort_t*)(ws + off); off += 262144;  // 2048*256 u16
    float*    Cg       = ws + off;              off += 524288;
    ushort_t* pos_inv  = (ushort_t*)(ws + off); off += 262144;  // 256*2048 u16
    // ---- zero prefix ends here ----
    ushort_t* HnewA    = (ushort_t*)(ws + off); off += 131072;  // 1024*256 u16
    ushort_t* HnewB    = (ushort_t*)(ws + off); off += 131072;
    float*    CnewA    = ws + off;              off += 262144;
    float*    CnewB    = ws + off;              off += 262144;
    ushort_t* BsatT    = (ushort_t*)(ws + off); off += 278528;  // 1024*544 u16
    float*    biasC    = ws + off;              off += 1024;
    ushort_t* s2r_rwT  = (ushort_t*)(ws + off); off += 131072;  // bf16 [4][256][256]
    ushort_t* s2r_lwT  = (ushort_t*)(ws + off); off += 131072;
    float*    W_recT   = ws + off;              off += 32768;   // 4*256*32

    const size_t zcount = 4096 + 16384 + 512 + 2048 + 262144 + 524288 + 262144;
    hipLaunchKernelGGL(k_zero, dim3(2048), dim3(256), 0, stream, ws, zcount);
    hipLaunchKernelGGL(k_bconv, dim3(1024), dim3(256), 0, stream, r2s_rw, W_sat, r2s_lw, BsatT);
    hipLaunchKernelGGL(k_biasC, dim3(4), dim3(256), 0, stream, r2s_lb, b_sat, biasC);
    hipLaunchKernelGGL(k_inv, dim3(T_STEPS), dim3(256), 0, stream, s_ids, pos_inv);
    hipLaunchKernelGGL(k_wtb, dim3(8, 8, 4), dim3(256), 0, stream, s2r_rw, s2r_rwT);
    hipLaunchKernelGGL(k_wtb, dim3(8, 8, 4), dim3(256), 0, stream, s2r_lw, s2r_lwT);
    hipLaunchKernelGGL(k_wrt, dim3(4), dim3(256), 0, stream, W_rec, W_recT);

    for (int t = 0; t < T_STEPS; t++) {
        const ushort_t* HnP = (t & 1) ? HnewA : HnewB;
        ushort_t*       HnC = (t & 1) ? HnewB : HnewA;
        const float*    CnP = (t & 1) ? CnewA : CnewB;
        float*          CnC = (t & 1) ? CnewB : CnewA;
        hipLaunchKernelGGL(k_step, dim3(288), dim3(256), 0, stream,
                           t, x_rec, x_sat, b_rec, s2r_lb,
                           s_ids, pos_inv, BsatT, biasC,
                           s2r_rwT, s2r_lwT, W_recT,
                           meanN, oldpart, crec, pre_rec,
                           Hg_bf, Cg, HnP, HnC, CnP, CnC);
    }
    hipLaunchKernelGGL(k_final, dim3(1), dim3(256), 0, stream,
                       pre_rec, crec, W_out, b_out, y_true, (float*)d_out);
}

// Round 8
// 4053.813 us; speedup vs baseline: 4.8059x; 1.3101x over previous
//
#include <hip/hip_runtime.h>
#include <cstddef>

#define T_STEPS  256
#define NSAT     1024
#define GSAT     2048
#define HID      256
#define IN_DIM   32
#define KTOT     544   // 256 h_sat + 32 x_sat + 256 h_rec (rl folded into GEMM)

typedef short  s16x8 __attribute__((ext_vector_type(8)));
typedef short  s16x4 __attribute__((ext_vector_type(4)));
typedef float  f32x4 __attribute__((ext_vector_type(4)));
typedef unsigned short ushort_t;

__device__ inline ushort_t f2bf(float f) {
    unsigned u = __builtin_bit_cast(unsigned, f);
    u += 0x7fffu + ((u >> 16) & 1u);
    return (ushort_t)(u >> 16);
}
__device__ inline float bf2f(ushort_t h) {
    unsigned u = ((unsigned)h) << 16;
    return __builtin_bit_cast(float, u);
}
__device__ inline float sigm(float x) { return 1.f / (1.f + __expf(-x)); }
__device__ inline float tanh_(float x) {
    float a = fabsf(x);
    float e = __expf(-2.f * a);
    float r = (1.f - e) / (1.f + e);
    return copysignf(r, x);
}

// ---------------- init: zero prefix ----------------
__global__ void k_zero(float* p, size_t n) {
    size_t i = (size_t)blockIdx.x * blockDim.x + threadIdx.x;
    size_t stride = (size_t)gridDim.x * blockDim.x;
    for (; i < n; i += stride) p[i] = 0.f;
}

// col order: c = (o>>3)*32 + g*8 + (o&7)  <->  g=(c>>3)&3, o=(c>>5)*8+(c&7)
__global__ void k_bconv(const float* __restrict__ r2s_rw,
                        const float* __restrict__ W_sat,
                        const float* __restrict__ r2s_lw,
                        ushort_t* __restrict__ BsatT) {
    int c = blockIdx.x;
    int g = (c >> 3) & 3, o = (c >> 5) * 8 + (c & 7);
    for (int k = threadIdx.x; k < KTOT; k += 256) {
        float v;
        if (k < 256)      v = r2s_rw[((size_t)g * 256 + k) * 256 + o];
        else if (k < 288) v = W_sat[((size_t)g * 32 + (k - 256)) * 256 + o];
        else              v = r2s_lw[((size_t)g * 256 + (k - 288)) * 256 + o];
        BsatT[(size_t)c * KTOT + k] = f2bf(v);
    }
}

__global__ void k_biasC(const float* __restrict__ r2s_lb, const float* __restrict__ b_sat,
                        float* __restrict__ biasC) {
    int c = blockIdx.x * 256 + threadIdx.x;
    if (c < 1024) {
        int g = (c >> 3) & 3, o = (c >> 5) * 8 + (c & 7);
        biasC[c] = r2s_lb[g * 256 + o] + b_sat[g * 256 + o];
    }
}

__global__ void k_inv(const int* __restrict__ s_ids, ushort_t* __restrict__ pos_inv) {
    int t = blockIdx.x;
    for (int n = threadIdx.x; n < NSAT; n += 256)
        pos_inv[(size_t)t * GSAT + s_ids[(size_t)t * NSAT + n]] = (ushort_t)(n + 1);
}

// asrc[t][n]: e<1024 -> row e of Hn(t-1); e>=1024 -> Hg row e-1024
__global__ void k_asrc(const int* __restrict__ s_ids, const ushort_t* __restrict__ pos_inv,
                       int* __restrict__ asrc) {
    int t = blockIdx.x;
    for (int n = threadIdx.x; n < NSAT; n += 256) {
        int j = s_ids[(size_t)t * NSAT + n];
        int e = 1024 + j;
        if (t > 0) {
            int p = (int)pos_inv[(size_t)(t - 1) * GSAT + j] - 1;
            if (p >= 0) e = p;
        }
        asrc[(size_t)t * NSAT + n] = e;
    }
}

// nxt_bits[t][w] bit i: sat (w*32+i) of step t is visible at step t+1
__global__ void k_bits(const int* __restrict__ s_ids, const ushort_t* __restrict__ pos_inv,
                       unsigned* __restrict__ nxt_bits) {
    int t = blockIdx.x, w = threadIdx.x;   // 32 threads
    unsigned bits = 0;
    if (t + 1 < T_STEPS) {
        for (int i = 0; i < 32; i++) {
            int j = s_ids[(size_t)t * NSAT + w * 32 + i];
            if (pos_inv[(size_t)(t + 1) * GSAT + j] > 0) bits |= (1u << i);
        }
    }
    nxt_bits[t * 32 + w] = bits;
}

// old list for launch t: sats in sids(t+1) not in sids(t).
// entry e>=0: row e of Hn(t-1); e<0: Hg row -(e+1). old_cnt must be pre-zeroed.
__global__ void k_old(const int* __restrict__ s_ids, const ushort_t* __restrict__ pos_inv,
                      short* __restrict__ old_src, int* __restrict__ old_cnt) {
    int t = blockIdx.x;
    if (t + 1 >= T_STEPS) return;
    for (int n = threadIdx.x; n < NSAT; n += 256) {
        int j = s_ids[(size_t)(t + 1) * NSAT + n];
        if (pos_inv[(size_t)t * GSAT + j] == 0) {
            int slot = atomicAdd(&old_cnt[t], 1);
            short e = (short)(-(j + 1));
            if (t > 0) {
                int p = (int)pos_inv[(size_t)(t - 1) * GSAT + j] - 1;
                if (p >= 0) e = (short)p;
            }
            old_src[(size_t)t * NSAT + slot] = e;
        }
    }
}

// transpose [4][256][256] (g,h,o) -> (g,o,h), bf16 output
__global__ void k_wtb(const float* __restrict__ in, ushort_t* __restrict__ outT) {
    __shared__ float tl[32][33];
    int g = blockIdx.z;
    int h0 = blockIdx.x * 32, o0 = blockIdx.y * 32;
    int lx = threadIdx.x & 31, ly = threadIdx.x >> 5;
#pragma unroll
    for (int i = 0; i < 32; i += 8)
        tl[ly + i][lx] = in[((size_t)g * 256 + h0 + ly + i) * 256 + o0 + lx];
    __syncthreads();
#pragma unroll
    for (int i = 0; i < 32; i += 8)
        outT[((size_t)g * 256 + o0 + ly + i) * 256 + h0 + lx] = f2bf(tl[lx][ly + i]);
}

__global__ void k_wrt(const float* __restrict__ W_rec, float* __restrict__ W_recT) {
    int idx = blockIdx.x * 256 + threadIdx.x;
    int g = idx >> 8, o = idx & 255;
#pragma unroll
    for (int i = 0; i < 32; i++)
        W_recT[(size_t)idx * 32 + i] = W_rec[((size_t)g * 32 + i) * 256 + o];
}

// ---------------- per-step kernel: grid 288 (256 sat + 32 rec), no cross-block waits
__launch_bounds__(256)
__global__ void k_step(int t,
    const float* __restrict__ x_rec, const float* __restrict__ x_sat,
    const float* __restrict__ b_rec, const float* __restrict__ s2r_lb,
    const int* __restrict__ s_ids, const int* __restrict__ asrc,
    const unsigned* __restrict__ nxt_bits,
    const short* __restrict__ old_src, const int* __restrict__ old_cnt,
    const ushort_t* __restrict__ BsatT, const float* __restrict__ biasC,
    const ushort_t* __restrict__ s2r_rwT, const ushort_t* __restrict__ s2r_lwT,
    const float* __restrict__ W_recT,
    float* __restrict__ meanN,    // [2][8*256]
    float* __restrict__ oldpart,  // [2][32*256]
    float* __restrict__ crec,     // [2][256]
    float* __restrict__ pre_rec,  // [2][1024]
    ushort_t* __restrict__ Hg_bf, float* __restrict__ Cg,
    const ushort_t* __restrict__ HnP, ushort_t* __restrict__ HnC,
    const float* __restrict__ CnP, float* __restrict__ CnC)
{
    const int b = blockIdx.x, tid = threadIdx.x;
    const float* preP  = pre_rec + ((t + 1) & 1) * 1024;  // pre_rec(t-1)
    const float* crecP = crec + (t & 1) * 256;            // crec(t-2)

    if (b < 256) {
        // ================= satellite block: by row-group, bxc col-group =========
        const int by = b >> 5, bxc = b & 31;
        __shared__ int      asrc_s[128];
        __shared__ ushort_t hr_bfs[256];
        __shared__ float    bias_s[32];
        __shared__ float    pre_s[128][33];

        if (tid < 128) asrc_s[tid] = asrc[(size_t)t * NSAT + by * 128 + tid];
        if (tid < 32) bias_s[tid] = biasC[bxc * 32 + tid];
        {   // redundant elementwise h_rec(t-1) from pre_rec(t-1), crec(t-2)
            float h = 0.f;
            if (t > 0) {
                float pi = preP[tid], pf = preP[256 + tid], pc = preP[512 + tid], po = preP[768 + tid];
                float cp = (t >= 2) ? crecP[tid] : 0.f;
                float cn = sigm(pf) * cp + sigm(pi) * tanh_(pc);
                h = sigm(po) * tanh_(cn);
            }
            hr_bfs[tid] = f2bf(h);
        }
        __syncthreads();

        // --- MFMA GEMM: 128 rows x 32 gate-cols, K = 256(h) + 32(x) + 256(h_rec) ---
        const int w = tid >> 6, l = tid & 63;
        const int lr = l & 15, kb = (l >> 4) * 8;
        const int r0 = w * 32 + lr, r1 = r0 + 16;
        const int e0 = asrc_s[r0], e1 = asrc_s[r1];
        const ushort_t* a0 = (e0 < 1024) ? HnP + (size_t)e0 * HID : Hg_bf + (size_t)(e0 - 1024) * HID;
        const ushort_t* a1 = (e1 < 1024) ? HnP + (size_t)e1 * HID : Hg_bf + (size_t)(e1 - 1024) * HID;
        const ushort_t* bp0 = BsatT + ((size_t)(bxc * 32 + lr)) * KTOT;
        const ushort_t* bp1 = bp0 + (size_t)16 * KTOT;
        f32x4 a00 = {0.f,0.f,0.f,0.f}, a01 = a00, a10 = a00, a11 = a00;
#pragma unroll
        for (int kc = 0; kc < 8; kc++) {
            int k0 = kc * 32 + kb;
            s16x8 af0 = *(const s16x8*)(a0 + k0);
            s16x8 af1 = *(const s16x8*)(a1 + k0);
            s16x8 bv0 = *(const s16x8*)(bp0 + k0);
            s16x8 bv1 = *(const s16x8*)(bp1 + k0);
            a00 = __builtin_amdgcn_mfma_f32_16x16x32_bf16(af0, bv0, a00, 0, 0, 0);
            a01 = __builtin_amdgcn_mfma_f32_16x16x32_bf16(af0, bv1, a01, 0, 0, 0);
            a10 = __builtin_amdgcn_mfma_f32_16x16x32_bf16(af1, bv0, a10, 0, 0, 0);
            a11 = __builtin_amdgcn_mfma_f32_16x16x32_bf16(af1, bv1, a11, 0, 0, 0);
        }
        {   // x segment (K = 256..287)
            const float* ax0 = x_sat + ((size_t)t * NSAT + by * 128 + r0) * IN_DIM + kb;
            const float* ax1 = x_sat + ((size_t)t * NSAT + by * 128 + r1) * IN_DIM + kb;
            f32x4 x00 = *(const f32x4*)ax0, x01 = *(const f32x4*)(ax0 + 4);
            f32x4 x10 = *(const f32x4*)ax1, x11 = *(const f32x4*)(ax1 + 4);
            s16x8 af0, af1;
#pragma unroll
            for (int e = 0; e < 4; e++) {
                af0[e] = (short)f2bf(x00[e]); af0[4 + e] = (short)f2bf(x01[e]);
                af1[e] = (short)f2bf(x10[e]); af1[4 + e] = (short)f2bf(x11[e]);
            }
            int k0 = 256 + kb;
            s16x8 bv0 = *(const s16x8*)(bp0 + k0);
            s16x8 bv1 = *(const s16x8*)(bp1 + k0);
            a00 = __builtin_amdgcn_mfma_f32_16x16x32_bf16(af0, bv0, a00, 0, 0, 0);
            a01 = __builtin_amdgcn_mfma_f32_16x16x32_bf16(af0, bv1, a01, 0, 0, 0);
            a10 = __builtin_amdgcn_mfma_f32_16x16x32_bf16(af1, bv0, a10, 0, 0, 0);
            a11 = __builtin_amdgcn_mfma_f32_16x16x32_bf16(af1, bv1, a11, 0, 0, 0);
        }
#pragma unroll
        for (int kc = 0; kc < 8; kc++) {   // h_rec segment (K = 288..543), A uniform
            int k0 = 288 + kc * 32 + kb;
            s16x8 af = *(const s16x8*)(hr_bfs + (k0 - 288));
            s16x8 bv0 = *(const s16x8*)(bp0 + k0);
            s16x8 bv1 = *(const s16x8*)(bp1 + k0);
            a00 = __builtin_amdgcn_mfma_f32_16x16x32_bf16(af, bv0, a00, 0, 0, 0);
            a01 = __builtin_amdgcn_mfma_f32_16x16x32_bf16(af, bv1, a01, 0, 0, 0);
            a10 = __builtin_amdgcn_mfma_f32_16x16x32_bf16(af, bv0, a10, 0, 0, 0);
            a11 = __builtin_amdgcn_mfma_f32_16x16x32_bf16(af, bv1, a11, 0, 0, 0);
        }
        // stage C (col=lane&15, row=(lane>>4)*4+reg)
#pragma unroll
        for (int rr = 0; rr < 4; rr++) {
            int ro = (l >> 4) * 4 + rr;
            pre_s[w * 32 + ro][lr]           = a00[rr];
            pre_s[w * 32 + ro][16 + lr]      = a01[rr];
            pre_s[w * 32 + 16 + ro][lr]      = a10[rr];
            pre_s[w * 32 + 16 + ro][16 + lr] = a11[rr];
        }
        __syncthreads();

        // --- epilogue: LSTM over 4 cells/thread, write HnC/CnC + meanN staging ---
        {
            int n = tid >> 1, oi0 = (tid & 1) * 4;
            int og0 = bxc * 8 + oi0;
            int en = asrc_s[n];
            int gr = by * 128 + n;
            const float* csrc = (en < 1024) ? CnP + (size_t)en * HID + og0
                                            : Cg + (size_t)(en - 1024) * HID + og0;
            f32x4 cold = *(const f32x4*)csrc;
            bool nxt = (t + 1 < T_STEPS) && ((nxt_bits[t * 32 + (gr >> 5)] >> (gr & 31)) & 1u);
            f32x4 cnew, hf; s16x4 hnew;
#pragma unroll
            for (int e = 0; e < 4; e++) {
                int oi = oi0 + e;
                float pi = pre_s[n][oi]      + bias_s[oi];
                float pf = pre_s[n][8 + oi]  + bias_s[8 + oi];
                float pc = pre_s[n][16 + oi] + bias_s[16 + oi];
                float po = pre_s[n][24 + oi] + bias_s[24 + oi];
                float ig = sigm(pi), fg = sigm(pf), tg = tanh_(pc), oo = sigm(po);
                float cn = fg * cold[e] + ig * tg;
                float hn = oo * tanh_(cn);
                cnew[e] = cn; hf[e] = hn;
                hnew[e] = (short)f2bf(hn);
            }
            *(f32x4*)(CnC + (size_t)gr * HID + og0) = cnew;
            *(s16x4*)(HnC + (size_t)gr * HID + og0) = hnew;
#pragma unroll
            for (int e = 0; e < 4; e++) pre_s[n][oi0 + e] = nxt ? hf[e] : 0.f;
        }
        __syncthreads();
        if (t + 1 < T_STEPS && tid < 8) {
            float s = 0.f;
            for (int n = 0; n < 128; n++) s += pre_s[n][tid];
            meanN[((t + 1) & 1) * 2048 + by * 256 + bxc * 8 + tid] = s;
        }

        // --- deferred scatter of step t-1 (rows disjoint from all step-t reads) ---
        if (t > 0) {
#pragma unroll
            for (int i = 0; i < 4; i++) {
                int n = b * 4 + i;
                int j = s_ids[(size_t)(t - 1) * NSAT + n];
                Hg_bf[(size_t)j * HID + tid] = HnP[(size_t)n * HID + tid];
                Cg[(size_t)j * HID + tid]    = CnP[(size_t)n * HID + tid];
            }
        }
    } else {
        // ================= rec block r: mean reduce -> pre_rec(t) -> oldpart(t+1) ==
        const int r = b - 256;
        __shared__ float mean_s[256], hr_s[256], xr_s[32];
        {   // reduce mean(t) from prev-launch partials
            float s = 0.f;
            const float* mp = meanN + (t & 1) * 2048;
#pragma unroll
            for (int p = 0; p < 8; p++) s += mp[p * 256 + tid];
            const float* op = oldpart + (t & 1) * 8192;
#pragma unroll 8
            for (int p = 0; p < 32; p++) s += op[p * 256 + tid];
            mean_s[tid] = s * (1.f / 1024.f);
        }
        {   // elementwise h_rec(t-1); block r==0 stores crec(t-1)
            float h = 0.f, cn = 0.f;
            if (t > 0) {
                float pi = preP[tid], pf = preP[256 + tid], pc = preP[512 + tid], po = preP[768 + tid];
                float cp = (t >= 2) ? crecP[tid] : 0.f;
                cn = sigm(pf) * cp + sigm(pi) * tanh_(pc);
                h = sigm(po) * tanh_(cn);
            }
            hr_s[tid] = h;
            if (r == 0 && t > 0) crec[((t + 1) & 1) * 256 + tid] = cn;
        }
        if (tid < 32) xr_s[tid] = x_rec[(size_t)t * IN_DIM + tid];
        __syncthreads();
        {   // pre_rec(t) matvec: 32 gate-outs per block (bf16 weights)
            const int combo = tid >> 3, sub = tid & 7;
            const int g = combo >> 3, oo = combo & 7;
            const int o = r * 8 + oo;
            const ushort_t* rwp = s2r_rwT + ((size_t)(g * 256 + o)) * 256 + sub * 32;
            const ushort_t* lwp = s2r_lwT + ((size_t)(g * 256 + o)) * 256 + sub * 32;
            float part = 0.f;
#pragma unroll
            for (int q = 0; q < 4; q++) {
                s16x8 a = *(const s16x8*)(rwp + q * 8);
                s16x8 c = *(const s16x8*)(lwp + q * 8);
#pragma unroll
                for (int e = 0; e < 8; e++) {
                    int h = sub * 32 + q * 8 + e;
                    part += hr_s[h] * bf2f((ushort_t)a[e]) + mean_s[h] * bf2f((ushort_t)c[e]);
                }
            }
            {
                f32x4 wx = *(const f32x4*)(W_recT + ((size_t)(g * 256 + o)) * 32 + sub * 4);
#pragma unroll
                for (int e = 0; e < 4; e++) part += xr_s[sub * 4 + e] * wx[e];
            }
            part += __shfl_down(part, 4);
            part += __shfl_down(part, 2);
            part += __shfl_down(part, 1);
            if (sub == 0)
                pre_rec[(t & 1) * 1024 + g * 256 + o] =
                    part + b_rec[g * HID + o] + s2r_lb[g * HID + o];
        }
        // oldpart(t+1): precomputed gather list, strided across 32 rec blocks
        if (t + 1 < T_STEPS) {
            float s = 0.f;
            const int m = old_cnt[t];
            const short* osp = old_src + (size_t)t * NSAT;
            for (int k = r; k < m; k += 32) {
                int e = osp[k];
                const ushort_t* hp = (e >= 0) ? HnP + (size_t)e * HID
                                              : Hg_bf + (size_t)(-(e + 1)) * HID;
                s += bf2f(hp[tid]);
            }
            oldpart[((t + 1) & 1) * 8192 + r * 256 + tid] = s;
        }
    }
}

// ---------------- final: elementwise h_rec(255) + output projection ----------------
__global__ void k_final(const float* __restrict__ pre_rec,
                        const float* __restrict__ crec,
                        const float* __restrict__ W_out,
                        const float* __restrict__ b_out,
                        const float* __restrict__ y_true,
                        float* __restrict__ out) {
    __shared__ float red[256];
    int o = threadIdx.x;
    const float* pre = pre_rec + ((T_STEPS - 1) & 1) * 1024;   // pre_rec(255)
    float pi = pre[o], pf = pre[256 + o], pc = pre[512 + o], po = pre[768 + o];
    float cp = crec[(T_STEPS & 1) * 256 + o];                  // crec(254)
    float cn = sigm(pf) * cp + sigm(pi) * tanh_(pc);
    float h = sigm(po) * tanh_(cn);
    for (int j = 0; j < 2; j++) {
        red[o] = h * W_out[o * 2 + j];
        __syncthreads();
        for (int s = 128; s > 0; s >>= 1) {
            if (o < s) red[o] += red[o + s];
            __syncthreads();
        }
        if (o == 0) out[j] = red[0] + b_out[j];
        __syncthreads();
    }
    if (o < 2) out[2 + o] = y_true[o];
}

extern "C" void kernel_launch(void* const* d_in, const int* in_sizes, int n_in,
                              void* d_out, int out_size, void* d_ws, size_t ws_size,
                              hipStream_t stream) {
    (void)in_sizes; (void)n_in; (void)out_size; (void)ws_size;
    const float* x_rec  = (const float*)d_in[0];
    const float* x_sat  = (const float*)d_in[1];
    const float* y_true = (const float*)d_in[2];
    const float* W_rec  = (const float*)d_in[3];
    const float* b_rec  = (const float*)d_in[4];
    const float* W_sat  = (const float*)d_in[5];
    const float* b_sat  = (const float*)d_in[6];
    const float* s2r_lw = (const float*)d_in[7];
    const float* s2r_lb = (const float*)d_in[8];
    const float* s2r_rw = (const float*)d_in[9];
    const float* r2s_lw = (const float*)d_in[10];
    const float* r2s_lb = (const float*)d_in[11];
    const float* r2s_rw = (const float*)d_in[12];
    const float* W_out  = (const float*)d_in[13];
    const float* b_out  = (const float*)d_in[14];
    const int*   s_ids  = (const int*)d_in[15];

    float* ws = (float*)d_ws;
    size_t off = 0;
    // ---- zeroed prefix ----
    float*    meanN    = ws + off;              off += 4096;    // [2][8*256]
    float*    oldpart  = ws + off;              off += 16384;   // [2][32*256]
    float*    crec     = ws + off;              off += 512;     // [2][256]
    float*    pre_rec  = ws + off;              off += 2048;    // [2][1024]
    int*      old_cnt  = (int*)(ws + off);      off += 256;     // [256]
    ushort_t* Hg_bf    = (ushort_t*)(ws + off); off += 262144;  // 2048*256 u16
    float*    Cg       = ws + off;              off += 524288;
    ushort_t* pos_inv  = (ushort_t*)(ws + off); off += 262144;  // 256*2048 u16
    // ---- zero prefix ends here ----
    int*      asrc     = (int*)(ws + off);      off += 262144;  // [256][1024] int
    unsigned* nxt_bits = (unsigned*)(ws + off); off += 8192;    // [256][32] u32
    short*    old_src  = (short*)(ws + off);    off += 131072;  // [256][1024] s16
    ushort_t* HnewA    = (ushort_t*)(ws + off); off += 131072;  // 1024*256 u16
    ushort_t* HnewB    = (ushort_t*)(ws + off); off += 131072;
    float*    CnewA    = ws + off;              off += 262144;
    float*    CnewB    = ws + off;              off += 262144;
    ushort_t* BsatT    = (ushort_t*)(ws + off); off += 278528;  // 1024*544 u16
    float*    biasC    = ws + off;              off += 1024;
    ushort_t* s2r_rwT  = (ushort_t*)(ws + off); off += 131072;  // bf16 [4][256][256]
    ushort_t* s2r_lwT  = (ushort_t*)(ws + off); off += 131072;
    float*    W_recT   = ws + off;              off += 32768;   // 4*256*32

    const size_t zcount = 4096 + 16384 + 512 + 2048 + 256 + 262144 + 524288 + 262144;
    hipLaunchKernelGGL(k_zero, dim3(2048), dim3(256), 0, stream, ws, zcount);
    hipLaunchKernelGGL(k_inv, dim3(T_STEPS), dim3(256), 0, stream, s_ids, pos_inv);
    hipLaunchKernelGGL(k_asrc, dim3(T_STEPS), dim3(256), 0, stream, s_ids, pos_inv, asrc);
    hipLaunchKernelGGL(k_bits, dim3(T_STEPS), dim3(32), 0, stream, s_ids, pos_inv, nxt_bits);
    hipLaunchKernelGGL(k_old, dim3(T_STEPS), dim3(256), 0, stream, s_ids, pos_inv, old_src, old_cnt);
    hipLaunchKernelGGL(k_bconv, dim3(1024), dim3(256), 0, stream, r2s_rw, W_sat, r2s_lw, BsatT);
    hipLaunchKernelGGL(k_biasC, dim3(4), dim3(256), 0, stream, r2s_lb, b_sat, biasC);
    hipLaunchKernelGGL(k_wtb, dim3(8, 8, 4), dim3(256), 0, stream, s2r_rw, s2r_rwT);
    hipLaunchKernelGGL(k_wtb, dim3(8, 8, 4), dim3(256), 0, stream, s2r_lw, s2r_lwT);
    hipLaunchKernelGGL(k_wrt, dim3(4), dim3(256), 0, stream, W_rec, W_recT);

    for (int t = 0; t < T_STEPS; t++) {
        const ushort_t* HnP = (t & 1) ? HnewA : HnewB;
        ushort_t*       HnC = (t & 1) ? HnewB : HnewA;
        const float*    CnP = (t & 1) ? CnewA : CnewB;
        float*          CnC = (t & 1) ? CnewB : CnewA;
        hipLaunchKernelGGL(k_step, dim3(288), dim3(256), 0, stream,
                           t, x_rec, x_sat, b_rec, s2r_lb,
                           s_ids, asrc, nxt_bits, old_src, old_cnt,
                           BsatT, biasC,
                           s2r_rwT, s2r_lwT, W_recT,
                           meanN, oldpart, crec, pre_rec,
                           Hg_bf, Cg, HnP, HnC, CnP, CnC);
    }
    hipLaunchKernelGGL(k_final, dim3(1), dim3(256), 0, stream,
                       pre_rec, crec, W_out, b_out, y_true, (float*)d_out);
}

// Round 9
// 3603.956 us; speedup vs baseline: 5.4058x; 1.1248x over previous
//
#include <hip/hip_runtime.h>
#include <cstddef>

#define T_STEPS  256
#define NSAT     1024
#define GSAT     2048
#define HID      256
#define IN_DIM   32
#define KTOT     544   // 256 h_sat + 32 x_sat + 256 h_rec (rl folded into GEMM)

typedef short  s16x8 __attribute__((ext_vector_type(8)));
typedef short  s16x4 __attribute__((ext_vector_type(4)));
typedef float  f32x4 __attribute__((ext_vector_type(4)));
typedef unsigned short ushort_t;

__device__ inline ushort_t f2bf(float f) {
    unsigned u = __builtin_bit_cast(unsigned, f);
    u += 0x7fffu + ((u >> 16) & 1u);
    return (ushort_t)(u >> 16);
}
__device__ inline float bf2f(ushort_t h) {
    unsigned u = ((unsigned)h) << 16;
    return __builtin_bit_cast(float, u);
}
__device__ inline float sigm(float x) { return 1.f / (1.f + __expf(-x)); }
__device__ inline float tanh_(float x) {
    float a = fabsf(x);
    float e = __expf(-2.f * a);
    float r = (1.f - e) / (1.f + e);
    return copysignf(r, x);
}

// ---------------- init: zero prefix ----------------
__global__ void k_zero(float* p, size_t n) {
    size_t i = (size_t)blockIdx.x * blockDim.x + threadIdx.x;
    size_t stride = (size_t)gridDim.x * blockDim.x;
    for (; i < n; i += stride) p[i] = 0.f;
}

// col order: c = (o>>3)*32 + g*8 + (o&7)  <->  g=(c>>3)&3, o=(c>>5)*8+(c&7)
__global__ void k_bconv(const float* __restrict__ r2s_rw,
                        const float* __restrict__ W_sat,
                        const float* __restrict__ r2s_lw,
                        ushort_t* __restrict__ BsatT) {
    int c = blockIdx.x;
    int g = (c >> 3) & 3, o = (c >> 5) * 8 + (c & 7);
    for (int k = threadIdx.x; k < KTOT; k += 256) {
        float v;
        if (k < 256)      v = r2s_rw[((size_t)g * 256 + k) * 256 + o];
        else if (k < 288) v = W_sat[((size_t)g * 32 + (k - 256)) * 256 + o];
        else              v = r2s_lw[((size_t)g * 256 + (k - 288)) * 256 + o];
        BsatT[(size_t)c * KTOT + k] = f2bf(v);
    }
}

__global__ void k_biasC(const float* __restrict__ r2s_lb, const float* __restrict__ b_sat,
                        float* __restrict__ biasC) {
    int c = blockIdx.x * 256 + threadIdx.x;
    if (c < 1024) {
        int g = (c >> 3) & 3, o = (c >> 5) * 8 + (c & 7);
        biasC[c] = r2s_lb[g * 256 + o] + b_sat[g * 256 + o];
    }
}

__global__ void k_inv(const int* __restrict__ s_ids, ushort_t* __restrict__ pos_inv) {
    int t = blockIdx.x;
    for (int n = threadIdx.x; n < NSAT; n += 256)
        pos_inv[(size_t)t * GSAT + s_ids[(size_t)t * NSAT + n]] = (ushort_t)(n + 1);
}

// asrc[t][n]: e<1024 -> row e of Hn(t-1); e>=1024 -> Hg row e-1024
__global__ void k_asrc(const int* __restrict__ s_ids, const ushort_t* __restrict__ pos_inv,
                       int* __restrict__ asrc) {
    int t = blockIdx.x;
    for (int n = threadIdx.x; n < NSAT; n += 256) {
        int j = s_ids[(size_t)t * NSAT + n];
        int e = 1024 + j;
        if (t > 0) {
            int p = (int)pos_inv[(size_t)(t - 1) * GSAT + j] - 1;
            if (p >= 0) e = p;
        }
        asrc[(size_t)t * NSAT + n] = e;
    }
}

// nxt_bits[t][w] bit i: sat (w*32+i) of step t is visible at step t+1
__global__ void k_bits(const int* __restrict__ s_ids, const ushort_t* __restrict__ pos_inv,
                       unsigned* __restrict__ nxt_bits) {
    int t = blockIdx.x, w = threadIdx.x;   // 32 threads
    unsigned bits = 0;
    if (t + 1 < T_STEPS) {
        for (int i = 0; i < 32; i++) {
            int j = s_ids[(size_t)t * NSAT + w * 32 + i];
            if (pos_inv[(size_t)(t + 1) * GSAT + j] > 0) bits |= (1u << i);
        }
    }
    nxt_bits[t * 32 + w] = bits;
}

// old list for launch t: sats in sids(t+1) not in sids(t).
// entry e>=0: row e of Hn(t-1); e<0: Hg row -(e+1). old_cnt must be pre-zeroed.
__global__ void k_old(const int* __restrict__ s_ids, const ushort_t* __restrict__ pos_inv,
                      short* __restrict__ old_src, int* __restrict__ old_cnt) {
    int t = blockIdx.x;
    if (t + 1 >= T_STEPS) return;
    for (int n = threadIdx.x; n < NSAT; n += 256) {
        int j = s_ids[(size_t)(t + 1) * NSAT + n];
        if (pos_inv[(size_t)t * GSAT + j] == 0) {
            int slot = atomicAdd(&old_cnt[t], 1);
            short e = (short)(-(j + 1));
            if (t > 0) {
                int p = (int)pos_inv[(size_t)(t - 1) * GSAT + j] - 1;
                if (p >= 0) e = (short)p;
            }
            old_src[(size_t)t * NSAT + slot] = e;
        }
    }
}

// transpose [4][256][256] (g,h,o) -> (g,o,h), bf16 output
__global__ void k_wtb(const float* __restrict__ in, ushort_t* __restrict__ outT) {
    __shared__ float tl[32][33];
    int g = blockIdx.z;
    int h0 = blockIdx.x * 32, o0 = blockIdx.y * 32;
    int lx = threadIdx.x & 31, ly = threadIdx.x >> 5;
#pragma unroll
    for (int i = 0; i < 32; i += 8)
        tl[ly + i][lx] = in[((size_t)g * 256 + h0 + ly + i) * 256 + o0 + lx];
    __syncthreads();
#pragma unroll
    for (int i = 0; i < 32; i += 8)
        outT[((size_t)g * 256 + o0 + ly + i) * 256 + h0 + lx] = f2bf(tl[lx][ly + i]);
}

__global__ void k_wrt(const float* __restrict__ W_rec, float* __restrict__ W_recT) {
    int idx = blockIdx.x * 256 + threadIdx.x;
    int g = idx >> 8, o = idx & 255;
#pragma unroll
    for (int i = 0; i < 32; i++)
        W_recT[(size_t)idx * 32 + i] = W_rec[((size_t)g * 32 + i) * 256 + o];
}

// ---------------- per-step kernel: grid 288 (256 sat + 32 rec), no cross-block waits
// Latency-pipelined: all independent loads issued at kernel entry (G7);
// first barrier deferred until after the h-seg/x-seg MFMAs.
__launch_bounds__(256)
__global__ void k_step(int t,
    const float* __restrict__ x_rec, const float* __restrict__ x_sat,
    const float* __restrict__ b_rec, const float* __restrict__ s2r_lb,
    const int* __restrict__ s_ids, const int* __restrict__ asrc,
    const unsigned* __restrict__ nxt_bits,
    const short* __restrict__ old_src, const int* __restrict__ old_cnt,
    const ushort_t* __restrict__ BsatT, const float* __restrict__ biasC,
    const ushort_t* __restrict__ s2r_rwT, const ushort_t* __restrict__ s2r_lwT,
    const float* __restrict__ W_recT,
    float* __restrict__ meanN,    // [2][8*256]
    float* __restrict__ oldpart,  // [2][32*256]
    float* __restrict__ crec,     // [2][256]
    float* __restrict__ pre_rec,  // [2][1024]
    ushort_t* __restrict__ Hg_bf, float* __restrict__ Cg,
    const ushort_t* __restrict__ HnP, ushort_t* __restrict__ HnC,
    const float* __restrict__ CnP, float* __restrict__ CnC)
{
    const int b = blockIdx.x, tid = threadIdx.x;
    const float* preP  = pre_rec + ((t + 1) & 1) * 1024;  // pre_rec(t-1)
    const float* crecP = crec + (t & 1) * 256;            // crec(t-2)

    if (b < 256) {
        // ================= satellite block: by row-group, bxc col-group =========
        const int by = b >> 5, bxc = b & 31;
        __shared__ ushort_t hr_bfs[256];
        __shared__ float    bias_s[32];
        __shared__ float    pre_s[128][33];

        const int w = tid >> 6, l = tid & 63;
        const int lr = l & 15, kb = (l >> 4) * 8;
        const int r0 = w * 32 + lr, r1 = r0 + 16;
        const int* asrc_t = asrc + (size_t)t * NSAT + by * 128;

        // ---- entry: issue ALL independent loads ----
        const int e0 = asrc_t[r0], e1 = asrc_t[r1];          // per-lane, no LDS/barrier
        if (tid < 32) bias_s[tid] = biasC[bxc * 32 + tid];
        // epilogue cold-C gather (2 dependent loads, full GEMM to hide under)
        const int n_ep = tid >> 1, oi0_ep = (tid & 1) * 4;
        const int og0_ep = bxc * 8 + oi0_ep;
        const int en_ep = asrc_t[n_ep];
        const float* csrc = (en_ep < 1024) ? CnP + (size_t)en_ep * HID + og0_ep
                                           : Cg + (size_t)(en_ep - 1024) * HID + og0_ep;
        f32x4 cold = *(const f32x4*)csrc;
        // scatter(t-1) source rows + target ids, consumed at the very end
        ushort_t shv[4]; float scv[4]; int sjp[4];
        if (t > 0) {
#pragma unroll
            for (int i = 0; i < 4; i++) {
                int n = b * 4 + i;
                sjp[i] = s_ids[(size_t)(t - 1) * NSAT + n];
                shv[i] = HnP[(size_t)n * HID + tid];
                scv[i] = CnP[(size_t)n * HID + tid];
            }
        }
        // h_rec(t-1) recompute (overlaps the A/B gathers below)
        {
            float h = 0.f;
            if (t > 0) {
                float pi = preP[tid], pf = preP[256 + tid], pc = preP[512 + tid], po = preP[768 + tid];
                float cp = (t >= 2) ? crecP[tid] : 0.f;
                float cn = sigm(pf) * cp + sigm(pi) * tanh_(pc);
                h = sigm(po) * tanh_(cn);
            }
            hr_bfs[tid] = f2bf(h);
        }

        // --- MFMA GEMM: 128 rows x 32 gate-cols, K = 256(h) + 32(x) + 256(h_rec) ---
        const ushort_t* a0 = (e0 < 1024) ? HnP + (size_t)e0 * HID : Hg_bf + (size_t)(e0 - 1024) * HID;
        const ushort_t* a1 = (e1 < 1024) ? HnP + (size_t)e1 * HID : Hg_bf + (size_t)(e1 - 1024) * HID;
        const ushort_t* bp0 = BsatT + ((size_t)(bxc * 32 + lr)) * KTOT;
        const ushort_t* bp1 = bp0 + (size_t)16 * KTOT;
        f32x4 a00 = {0.f,0.f,0.f,0.f}, a01 = a00, a10 = a00, a11 = a00;
#pragma unroll
        for (int kc = 0; kc < 8; kc++) {
            int k0 = kc * 32 + kb;
            s16x8 af0 = *(const s16x8*)(a0 + k0);
            s16x8 af1 = *(const s16x8*)(a1 + k0);
            s16x8 bv0 = *(const s16x8*)(bp0 + k0);
            s16x8 bv1 = *(const s16x8*)(bp1 + k0);
            a00 = __builtin_amdgcn_mfma_f32_16x16x32_bf16(af0, bv0, a00, 0, 0, 0);
            a01 = __builtin_amdgcn_mfma_f32_16x16x32_bf16(af0, bv1, a01, 0, 0, 0);
            a10 = __builtin_amdgcn_mfma_f32_16x16x32_bf16(af1, bv0, a10, 0, 0, 0);
            a11 = __builtin_amdgcn_mfma_f32_16x16x32_bf16(af1, bv1, a11, 0, 0, 0);
        }
        {   // x segment (K = 256..287)
            const float* ax0 = x_sat + ((size_t)t * NSAT + by * 128 + r0) * IN_DIM + kb;
            const float* ax1 = x_sat + ((size_t)t * NSAT + by * 128 + r1) * IN_DIM + kb;
            f32x4 x00 = *(const f32x4*)ax0, x01 = *(const f32x4*)(ax0 + 4);
            f32x4 x10 = *(const f32x4*)ax1, x11 = *(const f32x4*)(ax1 + 4);
            s16x8 af0, af1;
#pragma unroll
            for (int e = 0; e < 4; e++) {
                af0[e] = (short)f2bf(x00[e]); af0[4 + e] = (short)f2bf(x01[e]);
                af1[e] = (short)f2bf(x10[e]); af1[4 + e] = (short)f2bf(x11[e]);
            }
            int k0 = 256 + kb;
            s16x8 bv0 = *(const s16x8*)(bp0 + k0);
            s16x8 bv1 = *(const s16x8*)(bp1 + k0);
            a00 = __builtin_amdgcn_mfma_f32_16x16x32_bf16(af0, bv0, a00, 0, 0, 0);
            a01 = __builtin_amdgcn_mfma_f32_16x16x32_bf16(af0, bv1, a01, 0, 0, 0);
            a10 = __builtin_amdgcn_mfma_f32_16x16x32_bf16(af1, bv0, a10, 0, 0, 0);
            a11 = __builtin_amdgcn_mfma_f32_16x16x32_bf16(af1, bv1, a11, 0, 0, 0);
        }
        __syncthreads();   // publish hr_bfs (first and only pre-GEMM barrier)
#pragma unroll
        for (int kc = 0; kc < 8; kc++) {   // h_rec segment (K = 288..543), A uniform
            int k0 = 288 + kc * 32 + kb;
            s16x8 af = *(const s16x8*)(hr_bfs + (k0 - 288));
            s16x8 bv0 = *(const s16x8*)(bp0 + k0);
            s16x8 bv1 = *(const s16x8*)(bp1 + k0);
            a00 = __builtin_amdgcn_mfma_f32_16x16x32_bf16(af, bv0, a00, 0, 0, 0);
            a01 = __builtin_amdgcn_mfma_f32_16x16x32_bf16(af, bv1, a01, 0, 0, 0);
            a10 = __builtin_amdgcn_mfma_f32_16x16x32_bf16(af, bv0, a10, 0, 0, 0);
            a11 = __builtin_amdgcn_mfma_f32_16x16x32_bf16(af, bv1, a11, 0, 0, 0);
        }
        // stage C (col=lane&15, row=(lane>>4)*4+reg)
#pragma unroll
        for (int rr = 0; rr < 4; rr++) {
            int ro = (l >> 4) * 4 + rr;
            pre_s[w * 32 + ro][lr]           = a00[rr];
            pre_s[w * 32 + ro][16 + lr]      = a01[rr];
            pre_s[w * 32 + 16 + ro][lr]      = a10[rr];
            pre_s[w * 32 + 16 + ro][16 + lr] = a11[rr];
        }
        __syncthreads();

        // --- epilogue: LSTM over 4 cells/thread (cold-C preloaded) ---
        {
            int n = n_ep, oi0 = oi0_ep, og0 = og0_ep;
            int gr = by * 128 + n;
            bool nxt = (t + 1 < T_STEPS) && ((nxt_bits[t * 32 + (gr >> 5)] >> (gr & 31)) & 1u);
            f32x4 cnew, hf; s16x4 hnew;
#pragma unroll
            for (int e = 0; e < 4; e++) {
                int oi = oi0 + e;
                float pi = pre_s[n][oi]      + bias_s[oi];
                float pf = pre_s[n][8 + oi]  + bias_s[8 + oi];
                float pc = pre_s[n][16 + oi] + bias_s[16 + oi];
                float po = pre_s[n][24 + oi] + bias_s[24 + oi];
                float ig = sigm(pi), fg = sigm(pf), tg = tanh_(pc), oo = sigm(po);
                float cn = fg * cold[e] + ig * tg;
                float hn = oo * tanh_(cn);
                cnew[e] = cn; hf[e] = hn;
                hnew[e] = (short)f2bf(hn);
            }
            *(f32x4*)(CnC + (size_t)gr * HID + og0) = cnew;
            *(s16x4*)(HnC + (size_t)gr * HID + og0) = hnew;
#pragma unroll
            for (int e = 0; e < 4; e++) pre_s[n][oi0 + e] = nxt ? hf[e] : 0.f;
        }
        __syncthreads();
        if (t + 1 < T_STEPS && tid < 8) {
            float s = 0.f;
            for (int n = 0; n < 128; n++) s += pre_s[n][tid];
            meanN[((t + 1) & 1) * 2048 + by * 256 + bxc * 8 + tid] = s;
        }

        // --- deferred scatter of step t-1 (values preloaded at entry) ---
        if (t > 0) {
#pragma unroll
            for (int i = 0; i < 4; i++) {
                Hg_bf[(size_t)sjp[i] * HID + tid] = shv[i];
                Cg[(size_t)sjp[i] * HID + tid]    = scv[i];
            }
        }
    } else {
        // ================= rec block r: mean reduce -> oldpart(t+1) -> pre_rec(t) ==
        const int r = b - 256;
        __shared__ float mean_s[256], hr_s[256], xr_s[32];
        const int m_old = (t + 1 < T_STEPS) ? old_cnt[t] : 0;   // issued first
        {   // reduce mean(t) from prev-launch partials
            float s = 0.f;
            const float* mp = meanN + (t & 1) * 2048;
#pragma unroll
            for (int p = 0; p < 8; p++) s += mp[p * 256 + tid];
            const float* op = oldpart + (t & 1) * 8192;
#pragma unroll 8
            for (int p = 0; p < 32; p++) s += op[p * 256 + tid];
            mean_s[tid] = s * (1.f / 1024.f);
        }
        {   // elementwise h_rec(t-1); block r==0 stores crec(t-1)
            float h = 0.f, cn = 0.f;
            if (t > 0) {
                float pi = preP[tid], pf = preP[256 + tid], pc = preP[512 + tid], po = preP[768 + tid];
                float cp = (t >= 2) ? crecP[tid] : 0.f;
                cn = sigm(pf) * cp + sigm(pi) * tanh_(pc);
                h = sigm(po) * tanh_(cn);
            }
            hr_s[tid] = h;
            if (r == 0 && t > 0) crec[((t + 1) & 1) * 256 + tid] = cn;
        }
        if (tid < 32) xr_s[tid] = x_rec[(size_t)t * IN_DIM + tid];
        __syncthreads();
        // oldpart(t+1) gather issued BEFORE the matvec: its L3 latency hides under it
        float s_old = 0.f;
        {
            const short* osp = old_src + (size_t)t * NSAT;
#pragma unroll 2
            for (int k = r; k < m_old; k += 32) {
                int e = osp[k];
                const ushort_t* hp = (e >= 0) ? HnP + (size_t)e * HID
                                              : Hg_bf + (size_t)(-(e + 1)) * HID;
                s_old += bf2f(hp[tid]);
            }
        }
        {   // pre_rec(t) matvec: 32 gate-outs per block (bf16 weights)
            const int combo = tid >> 3, sub = tid & 7;
            const int g = combo >> 3, oo = combo & 7;
            const int o = r * 8 + oo;
            const ushort_t* rwp = s2r_rwT + ((size_t)(g * 256 + o)) * 256 + sub * 32;
            const ushort_t* lwp = s2r_lwT + ((size_t)(g * 256 + o)) * 256 + sub * 32;
            float part = 0.f;
#pragma unroll
            for (int q = 0; q < 4; q++) {
                s16x8 a = *(const s16x8*)(rwp + q * 8);
                s16x8 c = *(const s16x8*)(lwp + q * 8);
#pragma unroll
                for (int e = 0; e < 8; e++) {
                    int h = sub * 32 + q * 8 + e;
                    part += hr_s[h] * bf2f((ushort_t)a[e]) + mean_s[h] * bf2f((ushort_t)c[e]);
                }
            }
            {
                f32x4 wx = *(const f32x4*)(W_recT + ((size_t)(g * 256 + o)) * 32 + sub * 4);
#pragma unroll
                for (int e = 0; e < 4; e++) part += xr_s[sub * 4 + e] * wx[e];
            }
            part += __shfl_down(part, 4);
            part += __shfl_down(part, 2);
            part += __shfl_down(part, 1);
            if (sub == 0)
                pre_rec[(t & 1) * 1024 + g * 256 + o] =
                    part + b_rec[g * HID + o] + s2r_lb[g * HID + o];
        }
        if (t + 1 < T_STEPS)
            oldpart[((t + 1) & 1) * 8192 + r * 256 + tid] = s_old;
    }
}

// ---------------- final: elementwise h_rec(255) + output projection ----------------
__global__ void k_final(const float* __restrict__ pre_rec,
                        const float* __restrict__ crec,
                        const float* __restrict__ W_out,
                        const float* __restrict__ b_out,
                        const float* __restrict__ y_true,
                        float* __restrict__ out) {
    __shared__ float red[256];
    int o = threadIdx.x;
    const float* pre = pre_rec + ((T_STEPS - 1) & 1) * 1024;   // pre_rec(255)
    float pi = pre[o], pf = pre[256 + o], pc = pre[512 + o], po = pre[768 + o];
    float cp = crec[(T_STEPS & 1) * 256 + o];                  // crec(254)
    float cn = sigm(pf) * cp + sigm(pi) * tanh_(pc);
    float h = sigm(po) * tanh_(cn);
    for (int j = 0; j < 2; j++) {
        red[o] = h * W_out[o * 2 + j];
        __syncthreads();
        for (int s = 128; s > 0; s >>= 1) {
            if (o < s) red[o] += red[o + s];
            __syncthreads();
        }
        if (o == 0) out[j] = red[0] + b_out[j];
        __syncthreads();
    }
    if (o < 2) out[2 + o] = y_true[o];
}

extern "C" void kernel_launch(void* const* d_in, const int* in_sizes, int n_in,
                              void* d_out, int out_size, void* d_ws, size_t ws_size,
                              hipStream_t stream) {
    (void)in_sizes; (void)n_in; (void)out_size; (void)ws_size;
    const float* x_rec  = (const float*)d_in[0];
    const float* x_sat  = (const float*)d_in[1];
    const float* y_true = (const float*)d_in[2];
    const float* W_rec  = (const float*)d_in[3];
    const float* b_rec  = (const float*)d_in[4];
    const float* W_sat  = (const float*)d_in[5];
    const float* b_sat  = (const float*)d_in[6];
    const float* s2r_lw = (const float*)d_in[7];
    const float* s2r_lb = (const float*)d_in[8];
    const float* s2r_rw = (const float*)d_in[9];
    const float* r2s_lw = (const float*)d_in[10];
    const float* r2s_lb = (const float*)d_in[11];
    const float* r2s_rw = (const float*)d_in[12];
    const float* W_out  = (const float*)d_in[13];
    const float* b_out  = (const float*)d_in[14];
    const int*   s_ids  = (const int*)d_in[15];

    float* ws = (float*)d_ws;
    size_t off = 0;
    // ---- zeroed prefix ----
    float*    meanN    = ws + off;              off += 4096;    // [2][8*256]
    float*    oldpart  = ws + off;              off += 16384;   // [2][32*256]
    float*    crec     = ws + off;              off += 512;     // [2][256]
    float*    pre_rec  = ws + off;              off += 2048;    // [2][1024]
    int*      old_cnt  = (int*)(ws + off);      off += 256;     // [256]
    ushort_t* Hg_bf    = (ushort_t*)(ws + off); off += 262144;  // 2048*256 u16
    float*    Cg       = ws + off;              off += 524288;
    ushort_t* pos_inv  = (ushort_t*)(ws + off); off += 262144;  // 256*2048 u16
    // ---- zero prefix ends here ----
    int*      asrc     = (int*)(ws + off);      off += 262144;  // [256][1024] int
    unsigned* nxt_bits = (unsigned*)(ws + off); off += 8192;    // [256][32] u32
    short*    old_src  = (short*)(ws + off);    off += 131072;  // [256][1024] s16
    ushort_t* HnewA    = (ushort_t*)(ws + off); off += 131072;  // 1024*256 u16
    ushort_t* HnewB    = (ushort_t*)(ws + off); off += 131072;
    float*    CnewA    = ws + off;              off += 262144;
    float*    CnewB    = ws + off;              off += 262144;
    ushort_t* BsatT    = (ushort_t*)(ws + off); off += 278528;  // 1024*544 u16
    float*    biasC    = ws + off;              off += 1024;
    ushort_t* s2r_rwT  = (ushort_t*)(ws + off); off += 131072;  // bf16 [4][256][256]
    ushort_t* s2r_lwT  = (ushort_t*)(ws + off); off += 131072;
    float*    W_recT   = ws + off;              off += 32768;   // 4*256*32

    const size_t zcount = 4096 + 16384 + 512 + 2048 + 256 + 262144 + 524288 + 262144;
    hipLaunchKernelGGL(k_zero, dim3(2048), dim3(256), 0, stream, ws, zcount);
    hipLaunchKernelGGL(k_inv, dim3(T_STEPS), dim3(256), 0, stream, s_ids, pos_inv);
    hipLaunchKernelGGL(k_asrc, dim3(T_STEPS), dim3(256), 0, stream, s_ids, pos_inv, asrc);
    hipLaunchKernelGGL(k_bits, dim3(T_STEPS), dim3(32), 0, stream, s_ids, pos_inv, nxt_bits);
    hipLaunchKernelGGL(k_old, dim3(T_STEPS), dim3(256), 0, stream, s_ids, pos_inv, old_src, old_cnt);
    hipLaunchKernelGGL(k_bconv, dim3(1024), dim3(256), 0, stream, r2s_rw, W_sat, r2s_lw, BsatT);
    hipLaunchKernelGGL(k_biasC, dim3(4), dim3(256), 0, stream, r2s_lb, b_sat, biasC);
    hipLaunchKernelGGL(k_wtb, dim3(8, 8, 4), dim3(256), 0, stream, s2r_rw, s2r_rwT);
    hipLaunchKernelGGL(k_wtb, dim3(8, 8, 4), dim3(256), 0, stream, s2r_lw, s2r_lwT);
    hipLaunchKernelGGL(k_wrt, dim3(4), dim3(256), 0, stream, W_rec, W_recT);

    for (int t = 0; t < T_STEPS; t++) {
        const ushort_t* HnP = (t & 1) ? HnewA : HnewB;
        ushort_t*       HnC = (t & 1) ? HnewB : HnewA;
        const float*    CnP = (t & 1) ? CnewA : CnewB;
        float*          CnC = (t & 1) ? CnewB : CnewA;
        hipLaunchKernelGGL(k_step, dim3(288), dim3(256), 0, stream,
                           t, x_rec, x_sat, b_rec, s2r_lb,
                           s_ids, asrc, nxt_bits, old_src, old_cnt,
                           BsatT, biasC,
                           s2r_rwT, s2r_lwT, W_recT,
                           meanN, oldpart, crec, pre_rec,
                           Hg_bf, Cg, HnP, HnC, CnP, CnC);
    }
    hipLaunchKernelGGL(k_final, dim3(1), dim3(256), 0, stream,
                       pre_rec, crec, W_out, b_out, y_true, (float*)d_out);
}

// Round 10
// 3378.134 us; speedup vs baseline: 5.7671x; 1.0668x over previous
//
#include <hip/hip_runtime.h>
#include <cstddef>

#define T_STEPS  256
#define NSAT     1024
#define GSAT     2048
#define HID      256
#define IN_DIM   32
#define KTOT     288   // 256 h_sat + 32 x_sat (rl computed as VALU matvec, not in GEMM)

typedef short  s16x8 __attribute__((ext_vector_type(8)));
typedef short  s16x4 __attribute__((ext_vector_type(4)));
typedef float  f32x4 __attribute__((ext_vector_type(4)));
typedef unsigned short ushort_t;

__device__ inline ushort_t f2bf(float f) {
    unsigned u = __builtin_bit_cast(unsigned, f);
    u += 0x7fffu + ((u >> 16) & 1u);
    return (ushort_t)(u >> 16);
}
__device__ inline float bf2f(ushort_t h) {
    unsigned u = ((unsigned)h) << 16;
    return __builtin_bit_cast(float, u);
}
__device__ inline float sigm(float x) { return 1.f / (1.f + __expf(-x)); }
__device__ inline float tanh_(float x) {
    float a = fabsf(x);
    float e = __expf(-2.f * a);
    float r = (1.f - e) / (1.f + e);
    return copysignf(r, x);
}

// ---------------- init: zero prefix ----------------
__global__ void k_zero(float* p, size_t n) {
    size_t i = (size_t)blockIdx.x * blockDim.x + threadIdx.x;
    size_t stride = (size_t)gridDim.x * blockDim.x;
    for (; i < n; i += stride) p[i] = 0.f;
}

// col order: c = (o>>3)*32 + g*8 + (o&7)  <->  g=(c>>3)&3, o=(c>>5)*8+(c&7)
__global__ void k_bconv(const float* __restrict__ r2s_rw,
                        const float* __restrict__ W_sat,
                        ushort_t* __restrict__ BsatT) {
    int c = blockIdx.x;
    int g = (c >> 3) & 3, o = (c >> 5) * 8 + (c & 7);
    for (int k = threadIdx.x; k < KTOT; k += 256) {
        float v = (k < 256) ? r2s_rw[((size_t)g * 256 + k) * 256 + o]
                            : W_sat[((size_t)g * 32 + (k - 256)) * 256 + o];
        BsatT[(size_t)c * KTOT + k] = f2bf(v);
    }
}

// rlw_bf[c][h] = r2s_lw[g][h][o], bf16
__global__ void k_rlw(const float* __restrict__ r2s_lw, ushort_t* __restrict__ rlw_bf) {
    int c = blockIdx.x;
    int g = (c >> 3) & 3, o = (c >> 5) * 8 + (c & 7);
    int h = threadIdx.x;
    rlw_bf[(size_t)c * 256 + h] = f2bf(r2s_lw[((size_t)g * 256 + h) * 256 + o]);
}

__global__ void k_biasC(const float* __restrict__ r2s_lb, const float* __restrict__ b_sat,
                        float* __restrict__ biasC) {
    int c = blockIdx.x * 256 + threadIdx.x;
    if (c < 1024) {
        int g = (c >> 3) & 3, o = (c >> 5) * 8 + (c & 7);
        biasC[c] = r2s_lb[g * 256 + o] + b_sat[g * 256 + o];
    }
}

__global__ void k_inv(const int* __restrict__ s_ids, ushort_t* __restrict__ pos_inv) {
    int t = blockIdx.x;
    for (int n = threadIdx.x; n < NSAT; n += 256)
        pos_inv[(size_t)t * GSAT + s_ids[(size_t)t * NSAT + n]] = (ushort_t)(n + 1);
}

// asrc[t][n]: e<1024 -> row e of Hn(t-1); e>=1024 -> Hg row e-1024
__global__ void k_asrc(const int* __restrict__ s_ids, const ushort_t* __restrict__ pos_inv,
                       int* __restrict__ asrc) {
    int t = blockIdx.x;
    for (int n = threadIdx.x; n < NSAT; n += 256) {
        int j = s_ids[(size_t)t * NSAT + n];
        int e = 1024 + j;
        if (t > 0) {
            int p = (int)pos_inv[(size_t)(t - 1) * GSAT + j] - 1;
            if (p >= 0) e = p;
        }
        asrc[(size_t)t * NSAT + n] = e;
    }
}

// nxt_bits[t][w] bit i: sat (w*32+i) of step t is visible at step t+1
__global__ void k_bits(const int* __restrict__ s_ids, const ushort_t* __restrict__ pos_inv,
                       unsigned* __restrict__ nxt_bits) {
    int t = blockIdx.x, w = threadIdx.x;   // 32 threads
    unsigned bits = 0;
    if (t + 1 < T_STEPS) {
        for (int i = 0; i < 32; i++) {
            int j = s_ids[(size_t)t * NSAT + w * 32 + i];
            if (pos_inv[(size_t)(t + 1) * GSAT + j] > 0) bits |= (1u << i);
        }
    }
    nxt_bits[t * 32 + w] = bits;
}

// old list for launch t: sats in sids(t+1) not in sids(t).
// entry e>=0: row e of Hn(t-1); e<0: Hg row -(e+1). old_cnt pre-zeroed.
__global__ void k_old(const int* __restrict__ s_ids, const ushort_t* __restrict__ pos_inv,
                      short* __restrict__ old_src, int* __restrict__ old_cnt) {
    int t = blockIdx.x;
    if (t + 1 >= T_STEPS) return;
    for (int n = threadIdx.x; n < NSAT; n += 256) {
        int j = s_ids[(size_t)(t + 1) * NSAT + n];
        if (pos_inv[(size_t)t * GSAT + j] == 0) {
            int slot = atomicAdd(&old_cnt[t], 1);
            short e = (short)(-(j + 1));
            if (t > 0) {
                int p = (int)pos_inv[(size_t)(t - 1) * GSAT + j] - 1;
                if (p >= 0) e = (short)p;
            }
            old_src[(size_t)t * NSAT + slot] = e;
        }
    }
}

// leave list for launch t (t>=1): rows of sids(t-1) NOT in sids(t); park those only.
// packed (pos_in_prev << 16) | sat_id. lv_cnt pre-zeroed.
__global__ void k_lv(const int* __restrict__ s_ids, const ushort_t* __restrict__ pos_inv,
                     int* __restrict__ lv, int* __restrict__ lv_cnt) {
    int t = blockIdx.x;
    if (t == 0) return;
    for (int n = threadIdx.x; n < NSAT; n += 256) {
        int j = s_ids[(size_t)(t - 1) * NSAT + n];
        if (pos_inv[(size_t)t * GSAT + j] == 0) {
            int slot = atomicAdd(&lv_cnt[t], 1);
            lv[(size_t)t * NSAT + slot] = (n << 16) | j;
        }
    }
}

// transpose [4][256][256] (g,h,o) -> (g,o,h), bf16 output
__global__ void k_wtb(const float* __restrict__ in, ushort_t* __restrict__ outT) {
    __shared__ float tl[32][33];
    int g = blockIdx.z;
    int h0 = blockIdx.x * 32, o0 = blockIdx.y * 32;
    int lx = threadIdx.x & 31, ly = threadIdx.x >> 5;
#pragma unroll
    for (int i = 0; i < 32; i += 8)
        tl[ly + i][lx] = in[((size_t)g * 256 + h0 + ly + i) * 256 + o0 + lx];
    __syncthreads();
#pragma unroll
    for (int i = 0; i < 32; i += 8)
        outT[((size_t)g * 256 + o0 + ly + i) * 256 + h0 + lx] = f2bf(tl[lx][ly + i]);
}

__global__ void k_wrt(const float* __restrict__ W_rec, float* __restrict__ W_recT) {
    int idx = blockIdx.x * 256 + threadIdx.x;
    int g = idx >> 8, o = idx & 255;
#pragma unroll
    for (int i = 0; i < 32; i++)
        W_recT[(size_t)idx * 32 + i] = W_rec[((size_t)g * 32 + i) * 256 + o];
}

// ---------------- per-step kernel: grid 288 (256 sat + 32 rec), no cross-block waits
__launch_bounds__(256)
__global__ void k_step(int t,
    const float* __restrict__ x_rec, const float* __restrict__ x_sat,
    const float* __restrict__ b_rec, const float* __restrict__ s2r_lb,
    const int* __restrict__ asrc, const unsigned* __restrict__ nxt_bits,
    const short* __restrict__ old_src, const int* __restrict__ old_cnt,
    const int* __restrict__ lv, const int* __restrict__ lv_cnt,
    const ushort_t* __restrict__ BsatT, const ushort_t* __restrict__ rlw_bf,
    const float* __restrict__ biasC,
    const ushort_t* __restrict__ s2r_rwT, const ushort_t* __restrict__ s2r_lwT,
    const float* __restrict__ W_recT,
    float* __restrict__ meanN,    // [2][8*256]
    float* __restrict__ oldpart,  // [2][32*256]
    float* __restrict__ crec,     // [2][256]
    float* __restrict__ pre_rec,  // [2][1024]
    ushort_t* __restrict__ Hg_bf, ushort_t* __restrict__ Cg_bf,
    const ushort_t* __restrict__ HnP, ushort_t* __restrict__ HnC,
    const ushort_t* __restrict__ CnP, ushort_t* __restrict__ CnC)
{
    const int b = blockIdx.x, tid = threadIdx.x;
    const float* preP  = pre_rec + ((t + 1) & 1) * 1024;  // pre_rec(t-1)
    const float* crecP = crec + (t & 1) * 256;            // crec(t-2)

    if (b < 256) {
        // ================= satellite block: by row-group, bxc col-group =========
        const int by = b >> 5, bxc = b & 31;
        __shared__ ushort_t hr_bfs[256];
        __shared__ float    bias_s[32];
        __shared__ float    rl_s[32];
        __shared__ float    pre_s[128][33];

        const int w = tid >> 6, l = tid & 63;
        const int lr = l & 15, kb = (l >> 4) * 8;
        const int r0 = w * 32 + lr, r1 = r0 + 16;
        const int* asrc_t = asrc + (size_t)t * NSAT + by * 128;

        // ---- entry: issue ALL independent loads ----
        const int e0 = asrc_t[r0], e1 = asrc_t[r1];
        if (tid < 32) bias_s[tid] = biasC[bxc * 32 + tid];
        // epilogue cold-C gather (bf16), hidden under the GEMM
        const int n_ep = tid >> 1, oi0_ep = (tid & 1) * 4;
        const int og0_ep = bxc * 8 + oi0_ep;
        const int en_ep = asrc_t[n_ep];
        const ushort_t* csrc = (en_ep < 1024) ? CnP + (size_t)en_ep * HID + og0_ep
                                              : Cg_bf + (size_t)(en_ep - 1024) * HID + og0_ep;
        s16x4 cold4 = *(const s16x4*)csrc;
        // lazy-park preload (rows leaving the visible set; ~512/step over 256 blocks)
        const int lv_m = lv_cnt[t];
        ushort_t pH[4], pC[4]; int pJ[4];
#pragma unroll
        for (int i = 0; i < 4; i++) {
            int k = b + i * 256;
            if (k < lv_m) {
                int pv = lv[(size_t)t * NSAT + k];
                int pos = pv >> 16; pJ[i] = pv & 0xffff;
                pH[i] = HnP[(size_t)pos * HID + tid];
                pC[i] = CnP[(size_t)pos * HID + tid];
            } else pJ[i] = -1;
        }
        // h_rec(t-1) recompute (overlaps the A/B gathers below)
        {
            float h = 0.f;
            if (t > 0) {
                float pi = preP[tid], pf = preP[256 + tid], pc = preP[512 + tid], po = preP[768 + tid];
                float cp = (t >= 2) ? crecP[tid] : 0.f;
                float cn = sigm(pf) * cp + sigm(pi) * tanh_(pc);
                h = sigm(po) * tanh_(cn);
            }
            hr_bfs[tid] = f2bf(h);
        }

        // --- MFMA GEMM: 128 rows x 32 gate-cols, K = 256(h) + 32(x) ---
        const ushort_t* a0 = (e0 < 1024) ? HnP + (size_t)e0 * HID : Hg_bf + (size_t)(e0 - 1024) * HID;
        const ushort_t* a1 = (e1 < 1024) ? HnP + (size_t)e1 * HID : Hg_bf + (size_t)(e1 - 1024) * HID;
        const ushort_t* bp0 = BsatT + ((size_t)(bxc * 32 + lr)) * KTOT;
        const ushort_t* bp1 = bp0 + (size_t)16 * KTOT;
        f32x4 a00 = {0.f,0.f,0.f,0.f}, a01 = a00, a10 = a00, a11 = a00;
#pragma unroll
        for (int kc = 0; kc < 8; kc++) {
            int k0 = kc * 32 + kb;
            s16x8 af0 = *(const s16x8*)(a0 + k0);
            s16x8 af1 = *(const s16x8*)(a1 + k0);
            s16x8 bv0 = *(const s16x8*)(bp0 + k0);
            s16x8 bv1 = *(const s16x8*)(bp1 + k0);
            a00 = __builtin_amdgcn_mfma_f32_16x16x32_bf16(af0, bv0, a00, 0, 0, 0);
            a01 = __builtin_amdgcn_mfma_f32_16x16x32_bf16(af0, bv1, a01, 0, 0, 0);
            a10 = __builtin_amdgcn_mfma_f32_16x16x32_bf16(af1, bv0, a10, 0, 0, 0);
            a11 = __builtin_amdgcn_mfma_f32_16x16x32_bf16(af1, bv1, a11, 0, 0, 0);
        }
        {   // x segment (K = 256..287)
            const float* ax0 = x_sat + ((size_t)t * NSAT + by * 128 + r0) * IN_DIM + kb;
            const float* ax1 = x_sat + ((size_t)t * NSAT + by * 128 + r1) * IN_DIM + kb;
            f32x4 x00 = *(const f32x4*)ax0, x01 = *(const f32x4*)(ax0 + 4);
            f32x4 x10 = *(const f32x4*)ax1, x11 = *(const f32x4*)(ax1 + 4);
            s16x8 af0, af1;
#pragma unroll
            for (int e = 0; e < 4; e++) {
                af0[e] = (short)f2bf(x00[e]); af0[4 + e] = (short)f2bf(x01[e]);
                af1[e] = (short)f2bf(x10[e]); af1[4 + e] = (short)f2bf(x11[e]);
            }
            int k0 = 256 + kb;
            s16x8 bv0 = *(const s16x8*)(bp0 + k0);
            s16x8 bv1 = *(const s16x8*)(bp1 + k0);
            a00 = __builtin_amdgcn_mfma_f32_16x16x32_bf16(af0, bv0, a00, 0, 0, 0);
            a01 = __builtin_amdgcn_mfma_f32_16x16x32_bf16(af0, bv1, a01, 0, 0, 0);
            a10 = __builtin_amdgcn_mfma_f32_16x16x32_bf16(af1, bv0, a10, 0, 0, 0);
            a11 = __builtin_amdgcn_mfma_f32_16x16x32_bf16(af1, bv1, a11, 0, 0, 0);
        }
        // stage C (col=lane&15, row=(lane>>4)*4+reg)
#pragma unroll
        for (int rr = 0; rr < 4; rr++) {
            int ro = (l >> 4) * 4 + rr;
            pre_s[w * 32 + ro][lr]           = a00[rr];
            pre_s[w * 32 + ro][16 + lr]      = a01[rr];
            pre_s[w * 32 + 16 + ro][lr]      = a10[rr];
            pre_s[w * 32 + 16 + ro][16 + lr] = a11[rr];
        }
        __syncthreads();   // publish pre_s + hr_bfs + bias_s

        // --- rl matvec: rl[c] = r2s_lw^T.h_rec(t-1) + (r2s_lb + b_sat) ---
        {
            int c = tid >> 3, sub = tid & 7;
            const ushort_t* wp = rlw_bf + ((size_t)(bxc * 32 + c)) * 256 + sub * 32;
            float acc = 0.f;
#pragma unroll
            for (int q = 0; q < 4; q++) {
                s16x8 wv = *(const s16x8*)(wp + q * 8);
#pragma unroll
                for (int e = 0; e < 8; e++)
                    acc += bf2f(hr_bfs[sub * 32 + q * 8 + e]) * bf2f((ushort_t)wv[e]);
            }
            acc += __shfl_down(acc, 4);
            acc += __shfl_down(acc, 2);
            acc += __shfl_down(acc, 1);
            if (sub == 0) rl_s[c] = acc + bias_s[c];
        }
        __syncthreads();

        // --- epilogue: LSTM over 4 cells/thread (cold-C preloaded, bf16) ---
        {
            int n = n_ep, oi0 = oi0_ep, og0 = og0_ep;
            int gr = by * 128 + n;
            bool nxt = (t + 1 < T_STEPS) && ((nxt_bits[t * 32 + (gr >> 5)] >> (gr & 31)) & 1u);
            f32x4 hf; s16x4 cnew, hnew;
#pragma unroll
            for (int e = 0; e < 4; e++) {
                int oi = oi0 + e;
                float pi = pre_s[n][oi]      + rl_s[oi];
                float pf = pre_s[n][8 + oi]  + rl_s[8 + oi];
                float pc = pre_s[n][16 + oi] + rl_s[16 + oi];
                float po = pre_s[n][24 + oi] + rl_s[24 + oi];
                float ig = sigm(pi), fg = sigm(pf), tg = tanh_(pc), oo = sigm(po);
                float cn = fg * bf2f((ushort_t)cold4[e]) + ig * tg;
                float hn = oo * tanh_(cn);
                hf[e] = hn;
                cnew[e] = (short)f2bf(cn);
                hnew[e] = (short)f2bf(hn);
            }
            *(s16x4*)(CnC + (size_t)gr * HID + og0) = cnew;
            *(s16x4*)(HnC + (size_t)gr * HID + og0) = hnew;
#pragma unroll
            for (int e = 0; e < 4; e++) pre_s[n][oi0 + e] = nxt ? hf[e] : 0.f;
        }
        __syncthreads();
        if (t + 1 < T_STEPS && tid < 8) {
            float s = 0.f;
            for (int n = 0; n < 128; n++) s += pre_s[n][tid];
            meanN[((t + 1) & 1) * 2048 + by * 256 + bxc * 8 + tid] = s;
        }

        // --- lazy park of departing rows (values preloaded at entry) ---
#pragma unroll
        for (int i = 0; i < 4; i++) {
            if (pJ[i] >= 0) {
                Hg_bf[(size_t)pJ[i] * HID + tid] = pH[i];
                Cg_bf[(size_t)pJ[i] * HID + tid] = pC[i];
            }
        }
    } else {
        // ================= rec block r: mean reduce -> oldpart(t+1) -> pre_rec(t) ==
        const int r = b - 256;
        __shared__ float mean_s[256], hr_s[256], xr_s[32];
        const int m_old = (t + 1 < T_STEPS) ? old_cnt[t] : 0;   // issued first
        {   // reduce mean(t) from prev-launch partials
            float s = 0.f;
            const float* mp = meanN + (t & 1) * 2048;
#pragma unroll
            for (int p = 0; p < 8; p++) s += mp[p * 256 + tid];
            const float* op = oldpart + (t & 1) * 8192;
#pragma unroll 8
            for (int p = 0; p < 32; p++) s += op[p * 256 + tid];
            mean_s[tid] = s * (1.f / 1024.f);
        }
        {   // elementwise h_rec(t-1); block r==0 stores crec(t-1)
            float h = 0.f, cn = 0.f;
            if (t > 0) {
                float pi = preP[tid], pf = preP[256 + tid], pc = preP[512 + tid], po = preP[768 + tid];
                float cp = (t >= 2) ? crecP[tid] : 0.f;
                cn = sigm(pf) * cp + sigm(pi) * tanh_(pc);
                h = sigm(po) * tanh_(cn);
            }
            hr_s[tid] = h;
            if (r == 0 && t > 0) crec[((t + 1) & 1) * 256 + tid] = cn;
        }
        if (tid < 32) xr_s[tid] = x_rec[(size_t)t * IN_DIM + tid];
        __syncthreads();
        // oldpart(t+1) gather issued BEFORE the matvec: latency hides under it
        float s_old = 0.f;
        {
            const short* osp = old_src + (size_t)t * NSAT;
#pragma unroll 2
            for (int k = r; k < m_old; k += 32) {
                int e = osp[k];
                const ushort_t* hp = (e >= 0) ? HnP + (size_t)e * HID
                                              : Hg_bf + (size_t)(-(e + 1)) * HID;
                s_old += bf2f(hp[tid]);
            }
        }
        {   // pre_rec(t) matvec: 32 gate-outs per block (bf16 weights)
            const int combo = tid >> 3, sub = tid & 7;
            const int g = combo >> 3, oo = combo & 7;
            const int o = r * 8 + oo;
            const ushort_t* rwp = s2r_rwT + ((size_t)(g * 256 + o)) * 256 + sub * 32;
            const ushort_t* lwp = s2r_lwT + ((size_t)(g * 256 + o)) * 256 + sub * 32;
            float part = 0.f;
#pragma unroll
            for (int q = 0; q < 4; q++) {
                s16x8 a = *(const s16x8*)(rwp + q * 8);
                s16x8 c = *(const s16x8*)(lwp + q * 8);
#pragma unroll
                for (int e = 0; e < 8; e++) {
                    int h = sub * 32 + q * 8 + e;
                    part += hr_s[h] * bf2f((ushort_t)a[e]) + mean_s[h] * bf2f((ushort_t)c[e]);
                }
            }
            {
                f32x4 wx = *(const f32x4*)(W_recT + ((size_t)(g * 256 + o)) * 32 + sub * 4);
#pragma unroll
                for (int e = 0; e < 4; e++) part += xr_s[sub * 4 + e] * wx[e];
            }
            part += __shfl_down(part, 4);
            part += __shfl_down(part, 2);
            part += __shfl_down(part, 1);
            if (sub == 0)
                pre_rec[(t & 1) * 1024 + g * 256 + o] =
                    part + b_rec[g * HID + o] + s2r_lb[g * HID + o];
        }
        if (t + 1 < T_STEPS)
            oldpart[((t + 1) & 1) * 8192 + r * 256 + tid] = s_old;
    }
}

// ---------------- final: elementwise h_rec(255) + output projection ----------------
__global__ void k_final(const float* __restrict__ pre_rec,
                        const float* __restrict__ crec,
                        const float* __restrict__ W_out,
                        const float* __restrict__ b_out,
                        const float* __restrict__ y_true,
                        float* __restrict__ out) {
    __shared__ float red[256];
    int o = threadIdx.x;
    const float* pre = pre_rec + ((T_STEPS - 1) & 1) * 1024;   // pre_rec(255)
    float pi = pre[o], pf = pre[256 + o], pc = pre[512 + o], po = pre[768 + o];
    float cp = crec[(T_STEPS & 1) * 256 + o];                  // crec(254)
    float cn = sigm(pf) * cp + sigm(pi) * tanh_(pc);
    float h = sigm(po) * tanh_(cn);
    for (int j = 0; j < 2; j++) {
        red[o] = h * W_out[o * 2 + j];
        __syncthreads();
        for (int s = 128; s > 0; s >>= 1) {
            if (o < s) red[o] += red[o + s];
            __syncthreads();
        }
        if (o == 0) out[j] = red[0] + b_out[j];
        __syncthreads();
    }
    if (o < 2) out[2 + o] = y_true[o];
}

extern "C" void kernel_launch(void* const* d_in, const int* in_sizes, int n_in,
                              void* d_out, int out_size, void* d_ws, size_t ws_size,
                              hipStream_t stream) {
    (void)in_sizes; (void)n_in; (void)out_size; (void)ws_size;
    const float* x_rec  = (const float*)d_in[0];
    const float* x_sat  = (const float*)d_in[1];
    const float* y_true = (const float*)d_in[2];
    const float* W_rec  = (const float*)d_in[3];
    const float* b_rec  = (const float*)d_in[4];
    const float* W_sat  = (const float*)d_in[5];
    const float* b_sat  = (const float*)d_in[6];
    const float* s2r_lw = (const float*)d_in[7];
    const float* s2r_lb = (const float*)d_in[8];
    const float* s2r_rw = (const float*)d_in[9];
    const float* r2s_lw = (const float*)d_in[10];
    const float* r2s_lb = (const float*)d_in[11];
    const float* r2s_rw = (const float*)d_in[12];
    const float* W_out  = (const float*)d_in[13];
    const float* b_out  = (const float*)d_in[14];
    const int*   s_ids  = (const int*)d_in[15];

    float* ws = (float*)d_ws;
    size_t off = 0;
    // ---- zeroed prefix ----
    float*    meanN    = ws + off;              off += 4096;    // [2][8*256]
    float*    oldpart  = ws + off;              off += 16384;   // [2][32*256]
    float*    crec     = ws + off;              off += 512;     // [2][256]
    float*    pre_rec  = ws + off;              off += 2048;    // [2][1024]
    int*      old_cnt  = (int*)(ws + off);      off += 256;
    int*      lv_cnt   = (int*)(ws + off);      off += 256;
    ushort_t* Hg_bf    = (ushort_t*)(ws + off); off += 262144;  // 2048*256 u16
    ushort_t* Cg_bf    = (ushort_t*)(ws + off); off += 262144;  // 2048*256 u16
    ushort_t* pos_inv  = (ushort_t*)(ws + off); off += 262144;  // 256*2048 u16
    // ---- zero prefix ends here ----
    int*      asrc     = (int*)(ws + off);      off += 262144;  // [256][1024] int
    unsigned* nxt_bits = (unsigned*)(ws + off); off += 8192;    // [256][32] u32
    short*    old_src  = (short*)(ws + off);    off += 131072;  // [256][1024] s16
    int*      lv       = (int*)(ws + off);      off += 262144;  // [256][1024] int
    ushort_t* HnewA    = (ushort_t*)(ws + off); off += 131072;  // 1024*256 u16
    ushort_t* HnewB    = (ushort_t*)(ws + off); off += 131072;
    ushort_t* CnewA    = (ushort_t*)(ws + off); off += 131072;  // 1024*256 u16
    ushort_t* CnewB    = (ushort_t*)(ws + off); off += 131072;
    ushort_t* BsatT    = (ushort_t*)(ws + off); off += 147456;  // 1024*288 u16
    ushort_t* rlw_bf   = (ushort_t*)(ws + off); off += 131072;  // 1024*256 u16
    float*    biasC    = ws + off;              off += 1024;
    ushort_t* s2r_rwT  = (ushort_t*)(ws + off); off += 131072;  // bf16 [4][256][256]
    ushort_t* s2r_lwT  = (ushort_t*)(ws + off); off += 131072;
    float*    W_recT   = ws + off;              off += 32768;   // 4*256*32

    const size_t zcount = 4096 + 16384 + 512 + 2048 + 256 + 256
                        + 262144 + 262144 + 262144;
    hipLaunchKernelGGL(k_zero, dim3(2048), dim3(256), 0, stream, ws, zcount);
    hipLaunchKernelGGL(k_inv, dim3(T_STEPS), dim3(256), 0, stream, s_ids, pos_inv);
    hipLaunchKernelGGL(k_asrc, dim3(T_STEPS), dim3(256), 0, stream, s_ids, pos_inv, asrc);
    hipLaunchKernelGGL(k_bits, dim3(T_STEPS), dim3(32), 0, stream, s_ids, pos_inv, nxt_bits);
    hipLaunchKernelGGL(k_old, dim3(T_STEPS), dim3(256), 0, stream, s_ids, pos_inv, old_src, old_cnt);
    hipLaunchKernelGGL(k_lv, dim3(T_STEPS), dim3(256), 0, stream, s_ids, pos_inv, lv, lv_cnt);
    hipLaunchKernelGGL(k_bconv, dim3(1024), dim3(256), 0, stream, r2s_rw, W_sat, BsatT);
    hipLaunchKernelGGL(k_rlw, dim3(1024), dim3(256), 0, stream, r2s_lw, rlw_bf);
    hipLaunchKernelGGL(k_biasC, dim3(4), dim3(256), 0, stream, r2s_lb, b_sat, biasC);
    hipLaunchKernelGGL(k_wtb, dim3(8, 8, 4), dim3(256), 0, stream, s2r_rw, s2r_rwT);
    hipLaunchKernelGGL(k_wtb, dim3(8, 8, 4), dim3(256), 0, stream, s2r_lw, s2r_lwT);
    hipLaunchKernelGGL(k_wrt, dim3(4), dim3(256), 0, stream, W_rec, W_recT);

    for (int t = 0; t < T_STEPS; t++) {
        const ushort_t* HnP = (t & 1) ? HnewA : HnewB;
        ushort_t*       HnC = (t & 1) ? HnewB : HnewA;
        const ushort_t* CnP = (t & 1) ? CnewA : CnewB;
        ushort_t*       CnC = (t & 1) ? CnewB : CnewA;
        hipLaunchKernelGGL(k_step, dim3(288), dim3(256), 0, stream,
                           t, x_rec, x_sat, b_rec, s2r_lb,
                           asrc, nxt_bits, old_src, old_cnt, lv, lv_cnt,
                           BsatT, rlw_bf, biasC,
                           s2r_rwT, s2r_lwT, W_recT,
                           meanN, oldpart, crec, pre_rec,
                           Hg_bf, Cg_bf, HnP, HnC, CnP, CnC);
    }
    hipLaunchKernelGGL(k_final, dim3(1), dim3(256), 0, stream,
                       pre_rec, crec, W_out, b_out, y_true, (float*)d_out);
}